// Round 5
// baseline (198.628 us; speedup 1.0000x reference)
//
#include <hip/hip_runtime.h>
#include <stdint.h>

typedef unsigned short u16;
typedef __bf16 bf16x8 __attribute__((ext_vector_type(8)));
typedef float f32x4 __attribute__((ext_vector_type(4)));

__device__ __forceinline__ u16 f2bf(float f) {
  uint32_t u = __builtin_bit_cast(uint32_t, f);
  u += 0x7FFFu + ((u >> 16) & 1u);
  return (u16)(u >> 16);
}
__device__ __forceinline__ float bf2f(u16 v) {
  return __builtin_bit_cast(float, ((uint32_t)v) << 16);
}

#if __has_builtin(__builtin_amdgcn_exp2f)
__device__ __forceinline__ float exp2_fast(float x) { return __builtin_amdgcn_exp2f(x); }
#else
__device__ __forceinline__ float exp2_fast(float x) { return exp2f(x); }
#endif

__device__ __forceinline__ void gload_lds16(const u16* g, u16* l) {
  __builtin_amdgcn_global_load_lds(
      (const __attribute__((address_space(1))) uint32_t*)g,
      (__attribute__((address_space(3))) uint32_t*)l, 16, 0, 0);
}

// ---------------- conversions ----------------
__global__ __launch_bounds__(256) void convert_x_kernel(const float* __restrict__ in,
                                                        u16* __restrict__ out, int n) {
  int i = (blockIdx.x * 256 + threadIdx.x) * 8;
  if (i >= n) return;
  float4 a = *(const float4*)(in + i);
  float4 b = *(const float4*)(in + i + 4);
  union { u16 u[8]; uint4 v; } r;
  r.u[0] = f2bf(a.x); r.u[1] = f2bf(a.y); r.u[2] = f2bf(a.z); r.u[3] = f2bf(a.w);
  r.u[4] = f2bf(b.x); r.u[5] = f2bf(b.y); r.u[6] = f2bf(b.z); r.u[7] = f2bf(b.w);
  *(uint4*)(out + i) = r.v;
}

// WT[n][k] = W[k][n] * (n < scaleN ? scale : 1)
__global__ __launch_bounds__(256) void convert_wT_kernel(const float* __restrict__ W,
                                                         u16* __restrict__ WT,
                                                         int K, int N, int scaleN, float scale) {
  int id = blockIdx.x * 256 + threadIdx.x;
  if (id >= N * K) return;
  int k = id % K;
  int nn = id / K;
  float v = W[(size_t)k * N + nn];
  if (nn < scaleN) v *= scale;
  WT[id] = f2bf(v);
}

// ek/ev = label @ Wk/Wv   (16 rows x 512 cols, K=512), fp32 accumulate
__global__ __launch_bounds__(256) void cond_proj_kernel(const float* __restrict__ label,
                                                        const float* __restrict__ Wk,
                                                        const float* __restrict__ Wv,
                                                        u16* __restrict__ ek,
                                                        u16* __restrict__ ev) {
  int row = blockIdx.x & 15;
  const float* W = (blockIdx.x & 16) ? Wv : Wk;
  u16* o = (blockIdx.x & 16) ? ev : ek;
  int c0 = threadIdx.x, c1 = threadIdx.x + 256;
  float a0 = 0.f, a1 = 0.f;
  for (int k = 0; k < 512; ++k) {
    float lv = label[row * 512 + k];
    const float* wr = W + (size_t)k * 512;
    a0 = fmaf(lv, wr[c0], a0);
    a1 = fmaf(lv, wr[c1], a1);
  }
  o[row * 512 + c0] = f2bf(a0);
  o[row * 512 + c1] = f2bf(a1);
}

// ---------------- GEMM: C[M][N] = A[M][K] @ B^T[N][K], bf16 in, fp32 acc ----------------
template <int MODE>
__global__ __launch_bounds__(256) void gemm_bt_kernel(
    const u16* __restrict__ A, const u16* __restrict__ B,
    u16* __restrict__ OQ, u16* __restrict__ OKb, u16* __restrict__ OVT,
    float* __restrict__ OF, int K, int N) {
  __shared__ u16 As[128 * 64];
  __shared__ u16 Bs[128 * 64];
  const int tid = threadIdx.x;
  const int w = tid >> 6, lane = tid & 63;
  const int l15 = lane & 15, lg = lane >> 4;
  const int wr = w >> 1, wc = w & 1;
  const int bx = blockIdx.x, by = blockIdx.y;

  f32x4 acc[4][4] = {};

  const int lrow = lane >> 3, lcol = (lane & 7) * 8;
  const u16* Ag = A + (size_t)(bx * 128 + w * 32 + lrow) * K + lcol;
  const u16* Bg = B + (size_t)(by * 128 + w * 32 + lrow) * K + lcol;
  u16* Asw = &As[(w * 32) * 64];
  u16* Bsw = &Bs[(w * 32) * 64];

  for (int k0 = 0; k0 < K; k0 += 64) {
    if (k0) __syncthreads();
#pragma unroll
    for (int i = 0; i < 4; ++i) {
      gload_lds16(Ag + k0 + (size_t)(i * 8) * K, Asw + i * 8 * 64);
      gload_lds16(Bg + k0 + (size_t)(i * 8) * K, Bsw + i * 8 * 64);
    }
    __syncthreads();
#pragma unroll
    for (int ks = 0; ks < 2; ++ks) {
      bf16x8 a[4], b[4];
#pragma unroll
      for (int mi = 0; mi < 4; ++mi)
        a[mi] = *(const bf16x8*)&As[(wr * 64 + mi * 16 + l15) * 64 + ks * 32 + lg * 8];
#pragma unroll
      for (int ni = 0; ni < 4; ++ni)
        b[ni] = *(const bf16x8*)&Bs[(wc * 64 + ni * 16 + l15) * 64 + ks * 32 + lg * 8];
#pragma unroll
      for (int mi = 0; mi < 4; ++mi)
#pragma unroll
        for (int ni = 0; ni < 4; ++ni)
          acc[mi][ni] = __builtin_amdgcn_mfma_f32_16x16x32_bf16(a[mi], b[ni], acc[mi][ni], 0, 0, 0);
    }
  }

  const int row0 = bx * 128 + wr * 64 + lg * 4;
  if constexpr (MODE == 1) {
#pragma unroll
    for (int mi = 0; mi < 4; ++mi)
#pragma unroll
      for (int ni = 0; ni < 4; ++ni) {
        int col = by * 128 + wc * 64 + ni * 16 + l15;
#pragma unroll
        for (int r = 0; r < 4; ++r)
          OF[(size_t)(row0 + mi * 16 + r) * N + col] = acc[mi][ni][r];
      }
  } else {
    const int sect = by >> 2;                    // 0=q, 1=k, 2=v
    const int colL0 = (by & 3) * 128 + wc * 64;
    if (sect < 2) {
      u16* O = sect ? OKb : OQ;
#pragma unroll
      for (int mi = 0; mi < 4; ++mi)
#pragma unroll
        for (int ni = 0; ni < 4; ++ni) {
          int col = colL0 + ni * 16 + l15;
#pragma unroll
          for (int r = 0; r < 4; ++r)
            O[(size_t)(row0 + mi * 16 + r) * 512 + col] = f2bf(acc[mi][ni][r]);
        }
    } else {
#pragma unroll
      for (int mi = 0; mi < 4; ++mi)
#pragma unroll
        for (int ni = 0; ni < 4; ++ni) {
          int vcol = colL0 + ni * 16 + l15;
          int h = vcol >> 6, dh = vcol & 63;
          int rr = row0 + mi * 16;
          int bn = rr >> 10, t0 = rr & 1023;
          ushort4 pk;
          pk.x = f2bf(acc[mi][ni][0]);
          pk.y = f2bf(acc[mi][ni][1]);
          pk.z = f2bf(acc[mi][ni][2]);
          pk.w = f2bf(acc[mi][ni][3]);
          *(ushort4*)&OVT[(size_t)((bn * 8 + h) * 64 + dh) * 1024 + t0] = pk;
        }
    }
  }
}

// ---------------- fused flash attention v3 ----------------
// grid: 1024 = 128 heads x 8 q-tiles of 128. block: 128 (2 waves x 64 q-rows).
// KVBLK=32, double-buffered K/V staged via global_load_lds into XOR-swizzled
// linear tiles; P packed to u32 via cvt_pk; no-max exp2 softmax; ones-MFMA rowsum.
__global__ __launch_bounds__(128, 2) void attn_kernel(
    const u16* __restrict__ Qb, const u16* __restrict__ Kb, const u16* __restrict__ VTb,
    const u16* __restrict__ ekb, const u16* __restrict__ evb, u16* __restrict__ Ob) {
  // K tile: [kv=32][d=64] rows of 128B, swizzle byte ^= ((row&7)<<4)
  // V tile: [dh=64][kv=32] rows of 64B, swizzle byte ^= (((row>>2)&3)<<4)
  // P tile (per wave): [q=64][kv 32 + pad] stride 40 u16 (80B)
  __shared__ __align__(16) u16 Kl[2][2048];
  __shared__ __align__(16) u16 Vl[2][2048];
  __shared__ __align__(16) u16 Pl[2][64 * 40];

  const int tid = threadIdx.x;   // 0..127
  const int w = tid >> 6, lane = tid & 63;
  const int l15 = lane & 15, lg = lane >> 4;
  // XCD swizzle (1024 % 8 == 0, bijective)
  const int lb = (blockIdx.x & 7) * 128 + (blockIdx.x >> 3);
  const int head = lb >> 3, qt = lb & 7;
  const int bn = head >> 3, h = head & 7;
  const int q0 = qt * 128 + w * 64;

  // ---- staging address precompute (per thread; chunk = 16B) ----
  // K: chunks tid (rows 0-15) and tid+128 (rows 16-31)
  const int rK = tid >> 3;
  const int csK = (((tid & 7) * 16) ^ ((rK & 7) << 4)) >> 1;   // u16 units
  const u16* KgT = Kb + (size_t)(bn * 1024 + rK) * 512 + h * 64 + csK;
  // V: chunks tid (rows 0-31) and tid+128 (rows 32-63)
  const int rV = tid >> 2;
  const int csV = (((tid & 3) * 16) ^ (((rV >> 2) & 3) << 4)) >> 1;
  const u16* VgT = VTb + (size_t)(head * 64 + rV) * 1024 + csV;

  auto stage = [&](int buf, int jt) {
    const int j0 = jt * 32;
    gload_lds16(KgT + (size_t)j0 * 512, &Kl[buf][w * 512]);
    gload_lds16(KgT + (size_t)(j0 + 16) * 512, &Kl[buf][1024 + w * 512]);
    gload_lds16(VgT + j0, &Vl[buf][w * 512]);
    gload_lds16(VgT + j0 + (size_t)32 * 1024, &Vl[buf][1024 + w * 512]);
  };

  stage(0, 0);

  // ---- Q fragments: 4 sub-tiles x 2 k-halves ----
  bf16x8 qf[4][2];
#pragma unroll
  for (int qb = 0; qb < 4; ++qb) {
    const u16* qp = Qb + (size_t)(bn * 1024 + q0 + qb * 16 + l15) * 512 + h * 64 + lg * 8;
    qf[qb][0] = *(const bf16x8*)qp;
    qf[qb][1] = *(const bf16x8*)(qp + 32);
  }

  // ones B-fragment (col 0 all ones) for rowsum MFMA
  bf16x8 bones;
  {
    union { u16 u[8]; bf16x8 v; } ob;
    u16 one = (l15 == 0) ? (u16)0x3F80 : (u16)0;
#pragma unroll
    for (int j = 0; j < 8; ++j) ob.u[j] = one;
    bones = ob.v;
  }

  // conditioning token init
  f32x4 acc[4][4] = {};
  f32x4 acc5[4] = {};
  {
    const u16* ep = ekb + bn * 512 + h * 64 + lg * 8;
    bf16x8 e0 = *(const bf16x8*)ep;
    bf16x8 e1 = *(const bf16x8*)(ep + 32);
#pragma unroll
    for (int qb = 0; qb < 4; ++qb) {
      float s = 0.f;
#pragma unroll
      for (int j = 0; j < 8; ++j)
        s += (float)qf[qb][0][j] * (float)e0[j] + (float)qf[qb][1][j] * (float)e1[j];
      s += __shfl_xor(s, 16);
      s += __shfl_xor(s, 32);
      float pe[4];
#pragma unroll
      for (int r = 0; r < 4; ++r) {
        pe[r] = exp2_fast(__shfl(s, lg * 4 + r));
        acc5[qb][r] = (l15 == 0) ? pe[r] : 0.f;
      }
#pragma unroll
      for (int ni = 0; ni < 4; ++ni) {
        float ve = bf2f(evb[bn * 512 + h * 64 + ni * 16 + l15]);
#pragma unroll
        for (int r = 0; r < 4; ++r) acc[qb][ni][r] = pe[r] * ve;
      }
    }
  }

  u16* Pw = &Pl[w][0];
  const bool wlane = (l15 & 1) == 0;
  const int pcol = (l15 & ~1);

  int cur = 0;
  for (int jt = 0; jt < 32; ++jt) {
    __syncthreads();  // implicit vmcnt(0)+lgkmcnt(0) drain covers our gload_lds
    if (jt < 31) stage(cur ^ 1, jt + 1);

    // ---- S = Q @ K^T (64q x 32kv per wave) ----
    f32x4 s[4][2] = {};
#pragma unroll
    for (int ks = 0; ks < 2; ++ks)
#pragma unroll
      for (int ni = 0; ni < 2; ++ni) {
        const int row = ni * 16 + l15;
        bf16x8 kb = *(const bf16x8*)&Kl[cur][row * 64 + (((ks * 64 + lg * 16) ^ ((row & 7) << 4)) >> 1)];
#pragma unroll
        for (int qb = 0; qb < 4; ++qb)
          s[qb][ni] = __builtin_amdgcn_mfma_f32_16x16x32_bf16(qf[qb][ks], kb, s[qb][ni], 0, 0, 0);
      }

    // ---- p = exp2(s); pack pairs; store to per-wave Pl ----
#pragma unroll
    for (int qb = 0; qb < 4; ++qb)
#pragma unroll
      for (int ni = 0; ni < 2; ++ni)
#pragma unroll
        for (int r = 0; r < 4; ++r) {
          float p = exp2_fast(s[qb][ni][r]);
          float pp = __shfl_xor(p, 1);
          uint32_t pk;
          asm("v_cvt_pk_bf16_f32 %0, %1, %2" : "=v"(pk) : "v"(p), "v"(pp));
          if (wlane)
            *(uint32_t*)&Pw[(qb * 16 + lg * 4 + r) * 40 + ni * 16 + pcol] = pk;
        }

    // ---- acc += P @ V ; acc5 += P @ ones ----
#pragma unroll
    for (int qb = 0; qb < 4; ++qb) {
      bf16x8 pa = *(const bf16x8*)&Pw[(qb * 16 + l15) * 40 + lg * 8];
#pragma unroll
      for (int ni = 0; ni < 4; ++ni) {
        const int row = ni * 16 + l15;
        bf16x8 vb = *(const bf16x8*)&Vl[cur][row * 32 + (((lg * 16) ^ (((row >> 2) & 3) << 4)) >> 1)];
        acc[qb][ni] = __builtin_amdgcn_mfma_f32_16x16x32_bf16(pa, vb, acc[qb][ni], 0, 0, 0);
      }
      acc5[qb] = __builtin_amdgcn_mfma_f32_16x16x32_bf16(pa, bones, acc5[qb], 0, 0, 0);
    }

    cur ^= 1;
  }

  // ---- normalize + store ----
#pragma unroll
  for (int qb = 0; qb < 4; ++qb)
#pragma unroll
    for (int r = 0; r < 4; ++r) {
      float lsum = __shfl(acc5[qb][r], lg << 4);  // col-0 lane of this row group
      float inv = 1.0f / lsum;
      u16* op = Ob + (size_t)(bn * 1024 + q0 + qb * 16 + lg * 4 + r) * 512 + h * 64 + l15;
#pragma unroll
      for (int ni = 0; ni < 4; ++ni)
        op[ni * 16] = f2bf(acc[qb][ni][r] * inv);
    }
}

// ---------------- launcher ----------------
extern "C" void kernel_launch(void* const* d_in, const int* in_sizes, int n_in,
                              void* d_out, int out_size, void* d_ws, size_t ws_size,
                              hipStream_t stream) {
  (void)in_sizes; (void)n_in; (void)out_size; (void)ws_size;
  const float* x     = (const float*)d_in[0];
  const float* label = (const float*)d_in[1];
  const float* Wqkv  = (const float*)d_in[2];
  const float* Wk    = (const float*)d_in[3];
  const float* Wv    = (const float*)d_in[4];
  const float* Wout  = (const float*)d_in[5];
  float* out = (float*)d_out;

  char* ws = (char*)d_ws;
  u16* xb    = (u16*)(ws);                 // 16 MB, reused as attention-out after GEMM1
  u16* WqkvT = (u16*)(ws + 16777216);      // 1.5 MB
  u16* WoutT = (u16*)(ws + 18350080);      // 0.5 MB
  u16* ekb   = (u16*)(ws + 18874368);      // 16 KB
  u16* evb   = (u16*)(ws + 18890752);      // 16 KB
  u16* Qbuf  = (u16*)(ws + 18907136);      // 16 MB
  u16* Kbuf  = (u16*)(ws + 35684352);      // 16 MB
  u16* VTbuf = (u16*)(ws + 52461568);      // 16 MB

  // Q pre-scale folds softmax scale AND log2(e) for exp2-domain softmax
  const float qscale = 0.125f * 1.4426950408889634f;

  convert_x_kernel<<<4096, 256, 0, stream>>>(x, xb, 16384 * 512);
  convert_wT_kernel<<<3072, 256, 0, stream>>>(Wqkv, WqkvT, 512, 1536, 512, qscale);
  convert_wT_kernel<<<1024, 256, 0, stream>>>(Wout, WoutT, 512, 512, 0, 1.0f);
  cond_proj_kernel<<<32, 256, 0, stream>>>(label, Wk, Wv, ekb, evb);

  gemm_bt_kernel<0><<<dim3(128, 12), 256, 0, stream>>>(xb, WqkvT, Qbuf, Kbuf, VTbuf, nullptr, 512, 1536);

  attn_kernel<<<1024, 128, 0, stream>>>(Qbuf, Kbuf, VTbuf, ekb, evb, xb);

  gemm_bt_kernel<1><<<dim3(128, 4), 256, 0, stream>>>(xb, WoutT, nullptr, nullptr, nullptr, out, 512, 512);
}

// Round 6
// 155.271 us; speedup vs baseline: 1.2792x; 1.2792x over previous
//
#include <hip/hip_runtime.h>
#include <stdint.h>

typedef unsigned short u16;
typedef __bf16 bf16x8 __attribute__((ext_vector_type(8)));
typedef float f32x4 __attribute__((ext_vector_type(4)));
typedef float f32x16 __attribute__((ext_vector_type(16)));

__device__ __forceinline__ u16 f2bf(float f) {
  uint32_t u = __builtin_bit_cast(uint32_t, f);
  u += 0x7FFFu + ((u >> 16) & 1u);
  return (u16)(u >> 16);
}
__device__ __forceinline__ float bf2f(u16 v) {
  return __builtin_bit_cast(float, ((uint32_t)v) << 16);
}

#if __has_builtin(__builtin_amdgcn_exp2f)
__device__ __forceinline__ float exp2_fast(float x) { return __builtin_amdgcn_exp2f(x); }
#else
__device__ __forceinline__ float exp2_fast(float x) { return exp2f(x); }
#endif

__device__ __forceinline__ void gload_lds16(const u16* g, u16* l) {
  __builtin_amdgcn_global_load_lds(
      (const __attribute__((address_space(1))) uint32_t*)g,
      (__attribute__((address_space(3))) uint32_t*)l, 16, 0, 0);
}

__device__ __forceinline__ uint32_t cvtpk(float lo, float hi) {
  uint32_t r;
  asm("v_cvt_pk_bf16_f32 %0, %1, %2" : "=v"(r) : "v"(lo), "v"(hi));
  return r;
}
// v_permlane32_swap_b32: a.row1 <-> b.row0  (rows = 32-lane halves)
__device__ __forceinline__ void plswap(uint32_t& a, uint32_t& b) {
  asm volatile("v_permlane32_swap_b32 %0, %1" : "+v"(a), "+v"(b));
}

// ---------------- conversions ----------------
__global__ __launch_bounds__(256) void convert_x_kernel(const float* __restrict__ in,
                                                        u16* __restrict__ out, int n) {
  int i = (blockIdx.x * 256 + threadIdx.x) * 8;
  if (i >= n) return;
  float4 a = *(const float4*)(in + i);
  float4 b = *(const float4*)(in + i + 4);
  union { u16 u[8]; uint4 v; } r;
  r.u[0] = f2bf(a.x); r.u[1] = f2bf(a.y); r.u[2] = f2bf(a.z); r.u[3] = f2bf(a.w);
  r.u[4] = f2bf(b.x); r.u[5] = f2bf(b.y); r.u[6] = f2bf(b.z); r.u[7] = f2bf(b.w);
  *(uint4*)(out + i) = r.v;
}

__global__ __launch_bounds__(256) void convert_wT_kernel(const float* __restrict__ W,
                                                         u16* __restrict__ WT,
                                                         int K, int N, int scaleN, float scale) {
  int id = blockIdx.x * 256 + threadIdx.x;
  if (id >= N * K) return;
  int k = id % K;
  int nn = id / K;
  float v = W[(size_t)k * N + nn];
  if (nn < scaleN) v *= scale;
  WT[id] = f2bf(v);
}

__global__ __launch_bounds__(256) void cond_proj_kernel(const float* __restrict__ label,
                                                        const float* __restrict__ Wk,
                                                        const float* __restrict__ Wv,
                                                        u16* __restrict__ ek,
                                                        u16* __restrict__ ev) {
  int row = blockIdx.x & 15;
  const float* W = (blockIdx.x & 16) ? Wv : Wk;
  u16* o = (blockIdx.x & 16) ? ev : ek;
  int c0 = threadIdx.x, c1 = threadIdx.x + 256;
  float a0 = 0.f, a1 = 0.f;
  for (int k = 0; k < 512; ++k) {
    float lv = label[row * 512 + k];
    const float* wr = W + (size_t)k * 512;
    a0 = fmaf(lv, wr[c0], a0);
    a1 = fmaf(lv, wr[c1], a1);
  }
  o[row * 512 + c0] = f2bf(a0);
  o[row * 512 + c1] = f2bf(a1);
}

// ---------------- GEMM: C[M][N] = A[M][K] @ B^T[N][K], bf16 in, fp32 acc ----------------
template <int MODE>
__global__ __launch_bounds__(256) void gemm_bt_kernel(
    const u16* __restrict__ A, const u16* __restrict__ B,
    u16* __restrict__ OQ, u16* __restrict__ OKb, u16* __restrict__ OVT,
    float* __restrict__ OF, int K, int N) {
  __shared__ u16 As[128 * 64];
  __shared__ u16 Bs[128 * 64];
  const int tid = threadIdx.x;
  const int w = tid >> 6, lane = tid & 63;
  const int l15 = lane & 15, lg = lane >> 4;
  const int wr = w >> 1, wc = w & 1;

  // XCD-chunked swizzle: each XCD gets contiguous bx panels, by walks fastest.
  constexpr int NBY = (MODE == 0) ? 12 : 4;
  const int flat = blockIdx.y * gridDim.x + blockIdx.x;
  const int per = (gridDim.x * NBY) >> 3;
  const int swz = (flat & 7) * per + (flat >> 3);
  const int bx = swz / NBY, by = swz % NBY;

  f32x4 acc[4][4] = {};

  const int lrow = lane >> 3, lcol = (lane & 7) * 8;
  const u16* Ag = A + (size_t)(bx * 128 + w * 32 + lrow) * K + lcol;
  const u16* Bg = B + (size_t)(by * 128 + w * 32 + lrow) * K + lcol;
  u16* Asw = &As[(w * 32) * 64];
  u16* Bsw = &Bs[(w * 32) * 64];

  for (int k0 = 0; k0 < K; k0 += 64) {
    if (k0) __syncthreads();
#pragma unroll
    for (int i = 0; i < 4; ++i) {
      gload_lds16(Ag + k0 + (size_t)(i * 8) * K, Asw + i * 8 * 64);
      gload_lds16(Bg + k0 + (size_t)(i * 8) * K, Bsw + i * 8 * 64);
    }
    __syncthreads();
#pragma unroll
    for (int ks = 0; ks < 2; ++ks) {
      bf16x8 a[4], b[4];
#pragma unroll
      for (int mi = 0; mi < 4; ++mi)
        a[mi] = *(const bf16x8*)&As[(wr * 64 + mi * 16 + l15) * 64 + ks * 32 + lg * 8];
#pragma unroll
      for (int ni = 0; ni < 4; ++ni)
        b[ni] = *(const bf16x8*)&Bs[(wc * 64 + ni * 16 + l15) * 64 + ks * 32 + lg * 8];
#pragma unroll
      for (int mi = 0; mi < 4; ++mi)
#pragma unroll
        for (int ni = 0; ni < 4; ++ni)
          acc[mi][ni] = __builtin_amdgcn_mfma_f32_16x16x32_bf16(a[mi], b[ni], acc[mi][ni], 0, 0, 0);
    }
  }

  const int row0 = bx * 128 + wr * 64 + lg * 4;
  if constexpr (MODE == 1) {
#pragma unroll
    for (int mi = 0; mi < 4; ++mi)
#pragma unroll
      for (int ni = 0; ni < 4; ++ni) {
        int col = by * 128 + wc * 64 + ni * 16 + l15;
#pragma unroll
        for (int r = 0; r < 4; ++r)
          OF[(size_t)(row0 + mi * 16 + r) * N + col] = acc[mi][ni][r];
      }
  } else {
    const int sect = by >> 2;                    // 0=q, 1=k, 2=v
    const int colL0 = (by & 3) * 128 + wc * 64;
    if (sect < 2) {
      u16* O = sect ? OKb : OQ;
#pragma unroll
      for (int mi = 0; mi < 4; ++mi)
#pragma unroll
        for (int ni = 0; ni < 4; ++ni) {
          int col = colL0 + ni * 16 + l15;
#pragma unroll
          for (int r = 0; r < 4; ++r)
            O[(size_t)(row0 + mi * 16 + r) * 512 + col] = f2bf(acc[mi][ni][r]);
        }
    } else {
#pragma unroll
      for (int mi = 0; mi < 4; ++mi)
#pragma unroll
        for (int ni = 0; ni < 4; ++ni) {
          int vcol = colL0 + ni * 16 + l15;
          int h = vcol >> 6, dh = vcol & 63;
          int rr = row0 + mi * 16;
          int bn = rr >> 10, t0 = rr & 1023;
          ushort4 pk;
          pk.x = f2bf(acc[mi][ni][0]);
          pk.y = f2bf(acc[mi][ni][1]);
          pk.z = f2bf(acc[mi][ni][2]);
          pk.w = f2bf(acc[mi][ni][3]);
          *(ushort4*)&OVT[(size_t)((bn * 8 + h) * 64 + dh) * 1024 + t0] = pk;
        }
    }
  }
}

// ---------------- fused flash attention v4: 32x32 MFMA, in-register P (T12) ----------------
// grid: 512 = 128 heads x 4 q-tiles of 256. block: 256 (4 waves x 64 q).
// Swapped QK^T (A=K,B=Q) -> P lane-local; cvt_pk + permlane32_swap -> PV A-frags.
// No-max exp2 softmax; rowsum via all-ones-B MFMA (lane-local, zero shuffles).
__global__ __launch_bounds__(256, 2) void attn_kernel(
    const u16* __restrict__ Qb, const u16* __restrict__ Kb, const u16* __restrict__ VTb,
    const u16* __restrict__ ekb, const u16* __restrict__ evb, u16* __restrict__ Ob) {
  // Kl: [kv 64][d 64] u16, 16B chunks XOR-swizzled: chunk j stored at j^(row&7)
  // Vl: [dh 64][t 64] u16, same swizzle
  __shared__ __align__(16) u16 Kl[64 * 64];
  __shared__ __align__(16) u16 Vl[64 * 64];

  const int tid = threadIdx.x;
  const int w = tid >> 6, lane = tid & 63;
  const int l31 = lane & 31, hi = lane >> 5;
  // XCD swizzle (512 % 8 == 0, bijective): 4 q-tiles of a head share an XCD
  const int lb = (blockIdx.x & 7) * 64 + (blockIdx.x >> 3);
  const int head = lb >> 2, qt = lb & 3;
  const int bn = head >> 3, h = head & 7;
  const int q0 = qt * 256 + w * 64;

  // ---- staging setup: 256 threads x 16B = 32 rows/round, 2 rounds each for K,V ----
  const int sr = tid >> 3, sj = tid & 7;
  const int sdst = (sj ^ (sr & 7)) * 8;  // swizzled 16B chunk (u16 units)
  const u16* KgA = Kb + (size_t)(bn * 1024 + sr) * 512 + h * 64 + sj * 8;
  const u16* VgA = VTb + (size_t)(head * 64 + sr) * 1024 + sj * 8;
  u16* KlD = &Kl[sr * 64 + sdst];
  u16* VlD = &Vl[sr * 64 + sdst];

  uint4 kp0, kp1, vp0, vp1;
  {
    kp0 = *(const uint4*)(KgA);
    kp1 = *(const uint4*)(KgA + (size_t)32 * 512);
    vp0 = *(const uint4*)(VgA);
    vp1 = *(const uint4*)(VgA + (size_t)32 * 1024);
  }

  // ---- Q fragments (B-operand): lane holds col q=l31, k(d) = c*16 + hi*8 + j ----
  bf16x8 qf[2][4];
#pragma unroll
  for (int qs = 0; qs < 2; ++qs)
#pragma unroll
    for (int c = 0; c < 4; ++c)
      qf[qs][c] = *(const bf16x8*)(Qb + (size_t)(bn * 1024 + q0 + qs * 32 + l31) * 512 +
                                   h * 64 + c * 16 + hi * 8);

  // all-ones B-fragment (every col): rowsum MFMA output is lane-local in C layout
  bf16x8 bones1;
  {
    union { u16 u[8]; bf16x8 v; } ob;
#pragma unroll
    for (int j = 0; j < 8; ++j) ob.u[j] = (u16)0x3F80;
    bones1 = ob.v;
  }

  // ---- conditioning token via K=16 MFMA prologue: pe at k=0 ----
  f32x16 acc[2][2];
  f32x16 acc5[2];
  {
    float dot[2] = {0.f, 0.f};
#pragma unroll
    for (int c = 0; c < 4; ++c) {
      bf16x8 ekf = *(const bf16x8*)(ekb + bn * 512 + h * 64 + c * 16 + hi * 8);
#pragma unroll
      for (int qs = 0; qs < 2; ++qs)
#pragma unroll
        for (int j = 0; j < 8; ++j)
          dot[qs] += (float)qf[qs][c][j] * (float)ekf[j];
    }
    union { u16 u[8]; bf16x8 v; } pef[2], evf[2];
#pragma unroll
    for (int qs = 0; qs < 2; ++qs) {
      uint32_t a = __builtin_bit_cast(uint32_t, dot[qs]), b = a;
      plswap(a, b);
      float part = (lane < 32) ? __builtin_bit_cast(float, b) : __builtin_bit_cast(float, a);
      float pe = exp2_fast(dot[qs] + part);
#pragma unroll
      for (int j = 0; j < 8; ++j) pef[qs].u[j] = 0;
      if (hi == 0) pef[qs].u[0] = f2bf(pe);
    }
#pragma unroll
    for (int dt = 0; dt < 2; ++dt) {
#pragma unroll
      for (int j = 0; j < 8; ++j) evf[dt].u[j] = 0;
      if (hi == 0) evf[dt].u[0] = evb[bn * 512 + h * 64 + dt * 32 + l31];
    }
    f32x16 z = {};
#pragma unroll
    for (int qs = 0; qs < 2; ++qs) {
#pragma unroll
      for (int dt = 0; dt < 2; ++dt)
        acc[qs][dt] = __builtin_amdgcn_mfma_f32_32x32x16_bf16(pef[qs].v, evf[dt].v, z, 0, 0, 0);
      acc5[qs] = __builtin_amdgcn_mfma_f32_32x32x16_bf16(pef[qs].v, bones1, z, 0, 0, 0);
    }
  }

  // ---- main loop over 16 K/V tiles of 64 ----
  for (int jt = 0; jt < 16; ++jt) {
    __syncthreads();
    *(uint4*)(KlD) = kp0;
    *(uint4*)(KlD + 32 * 64) = kp1;
    *(uint4*)(VlD) = vp0;
    *(uint4*)(VlD + 32 * 64) = vp1;
    __syncthreads();

    if (jt < 15) {
      const int j0 = (jt + 1) * 64;
      kp0 = *(const uint4*)(KgA + (size_t)j0 * 512);
      kp1 = *(const uint4*)(KgA + (size_t)(j0 + 32) * 512);
      vp0 = *(const uint4*)(VgA + j0);
      vp1 = *(const uint4*)(VgA + j0 + (size_t)32 * 1024);
    }

#pragma unroll
    for (int sub = 0; sub < 2; ++sub) {
      // K A-frags: lane row kv = sub*32 + l31, k(d) chunk = c*2+hi
      const int rk = sub * 32 + l31;
      bf16x8 kb[4];
#pragma unroll
      for (int c = 0; c < 4; ++c)
        kb[c] = *(const bf16x8*)&Kl[rk * 64 + (((c * 2 + hi) ^ (rk & 7)) * 8)];

      // S^T = K @ Q^T : D[kv][q], col=q=l31, row=kv=(r&3)+8*(r>>2)+4*hi
      f32x16 s[2] = {};
#pragma unroll
      for (int qs = 0; qs < 2; ++qs)
#pragma unroll
        for (int c = 0; c < 4; ++c)
          s[qs] = __builtin_amdgcn_mfma_f32_32x32x16_bf16(kb[c], qf[qs][c], s[qs], 0, 0, 0);

      // exp2 -> pack -> permlane swap -> PV A-frags (kv chunks of 16)
      bf16x8 pa[2][2];
#pragma unroll
      for (int qs = 0; qs < 2; ++qs) {
        uint32_t wd[8];
#pragma unroll
        for (int i = 0; i < 8; ++i)
          wd[i] = cvtpk(exp2_fast(s[qs][2 * i]), exp2_fast(s[qs][2 * i + 1]));
        plswap(wd[0], wd[2]);
        plswap(wd[1], wd[3]);
        plswap(wd[4], wd[6]);
        plswap(wd[5], wd[7]);
        union { uint32_t w[4]; bf16x8 v; } f0, f1;
        f0.w[0] = wd[0]; f0.w[1] = wd[1]; f0.w[2] = wd[2]; f0.w[3] = wd[3];
        f1.w[0] = wd[4]; f1.w[1] = wd[5]; f1.w[2] = wd[6]; f1.w[3] = wd[7];
        pa[qs][0] = f0.v;
        pa[qs][1] = f1.v;
      }

      // PV: acc[qs][dt] += P @ V ; rowsum via all-ones B
#pragma unroll
      for (int dt = 0; dt < 2; ++dt) {
        const int rv = dt * 32 + l31;
#pragma unroll
        for (int ch = 0; ch < 2; ++ch) {
          bf16x8 vb = *(const bf16x8*)&Vl[rv * 64 + (((sub * 4 + ch * 2 + hi) ^ (rv & 7)) * 8)];
#pragma unroll
          for (int qs = 0; qs < 2; ++qs)
            acc[qs][dt] = __builtin_amdgcn_mfma_f32_32x32x16_bf16(pa[qs][ch], vb, acc[qs][dt], 0, 0, 0);
        }
      }
#pragma unroll
      for (int qs = 0; qs < 2; ++qs)
#pragma unroll
        for (int ch = 0; ch < 2; ++ch)
          acc5[qs] = __builtin_amdgcn_mfma_f32_32x32x16_bf16(pa[qs][ch], bones1, acc5[qs], 0, 0, 0);
    }
  }

  // ---- normalize + store: row q = (r&3)+8*(r>>2)+4*hi (lane-local rowsum!) ----
#pragma unroll
  for (int qs = 0; qs < 2; ++qs)
#pragma unroll
    for (int r = 0; r < 16; ++r) {
      const float inv = 1.0f / acc5[qs][r];
      const int q = q0 + qs * 32 + (r & 3) + 8 * (r >> 2) + 4 * hi;
      u16* op = Ob + (size_t)(bn * 1024 + q) * 512 + h * 64 + l31;
      op[0] = f2bf(acc[qs][0][r] * inv);
      op[32] = f2bf(acc[qs][1][r] * inv);
    }
}

// ---------------- launcher ----------------
extern "C" void kernel_launch(void* const* d_in, const int* in_sizes, int n_in,
                              void* d_out, int out_size, void* d_ws, size_t ws_size,
                              hipStream_t stream) {
  (void)in_sizes; (void)n_in; (void)out_size; (void)ws_size;
  const float* x     = (const float*)d_in[0];
  const float* label = (const float*)d_in[1];
  const float* Wqkv  = (const float*)d_in[2];
  const float* Wk    = (const float*)d_in[3];
  const float* Wv    = (const float*)d_in[4];
  const float* Wout  = (const float*)d_in[5];
  float* out = (float*)d_out;

  char* ws = (char*)d_ws;
  u16* xb    = (u16*)(ws);                 // 16 MB, reused as attention-out after GEMM1
  u16* WqkvT = (u16*)(ws + 16777216);      // 1.5 MB
  u16* WoutT = (u16*)(ws + 18350080);      // 0.5 MB
  u16* ekb   = (u16*)(ws + 18874368);      // 16 KB
  u16* evb   = (u16*)(ws + 18890752);      // 16 KB
  u16* Qbuf  = (u16*)(ws + 18907136);      // 16 MB
  u16* Kbuf  = (u16*)(ws + 35684352);      // 16 MB
  u16* VTbuf = (u16*)(ws + 52461568);      // 16 MB

  // Q pre-scale folds softmax scale AND log2(e) for exp2-domain softmax
  const float qscale = 0.125f * 1.4426950408889634f;

  convert_x_kernel<<<4096, 256, 0, stream>>>(x, xb, 16384 * 512);
  convert_wT_kernel<<<3072, 256, 0, stream>>>(Wqkv, WqkvT, 512, 1536, 512, qscale);
  convert_wT_kernel<<<1024, 256, 0, stream>>>(Wout, WoutT, 512, 512, 0, 1.0f);
  cond_proj_kernel<<<32, 256, 0, stream>>>(label, Wk, Wv, ekb, evb);

  gemm_bt_kernel<0><<<dim3(128, 12), 256, 0, stream>>>(xb, WqkvT, Qbuf, Kbuf, VTbuf, nullptr, 512, 1536);

  attn_kernel<<<512, 256, 0, stream>>>(Qbuf, Kbuf, VTbuf, ekb, evb, xb);

  gemm_bt_kernel<1><<<dim3(128, 4), 256, 0, stream>>>(xb, WoutT, nullptr, nullptr, nullptr, out, 512, 512);
}

// Round 7
// 139.962 us; speedup vs baseline: 1.4191x; 1.1094x over previous
//
#include <hip/hip_runtime.h>
#include <stdint.h>

typedef unsigned short u16;
typedef __bf16 bf16x8 __attribute__((ext_vector_type(8)));
typedef float f32x4 __attribute__((ext_vector_type(4)));
typedef float f32x16 __attribute__((ext_vector_type(16)));

__device__ __forceinline__ u16 f2bf(float f) {
  uint32_t u = __builtin_bit_cast(uint32_t, f);
  u += 0x7FFFu + ((u >> 16) & 1u);
  return (u16)(u >> 16);
}
__device__ __forceinline__ float bf2f(u16 v) {
  return __builtin_bit_cast(float, ((uint32_t)v) << 16);
}

#if __has_builtin(__builtin_amdgcn_exp2f)
__device__ __forceinline__ float exp2_fast(float x) { return __builtin_amdgcn_exp2f(x); }
#else
__device__ __forceinline__ float exp2_fast(float x) { return exp2f(x); }
#endif

__device__ __forceinline__ void gload_lds16(const u16* g, u16* l) {
  __builtin_amdgcn_global_load_lds(
      (const __attribute__((address_space(1))) uint32_t*)g,
      (__attribute__((address_space(3))) uint32_t*)l, 16, 0, 0);
}

__device__ __forceinline__ uint32_t cvtpk(float lo, float hi) {
  uint32_t r;
  asm("v_cvt_pk_bf16_f32 %0, %1, %2" : "=v"(r) : "v"(lo), "v"(hi));
  return r;
}
// v_permlane32_swap_b32: a.row1 <-> b.row0  (rows = 32-lane halves)
__device__ __forceinline__ void plswap(uint32_t& a, uint32_t& b) {
  asm volatile("v_permlane32_swap_b32 %0, %1" : "+v"(a), "+v"(b));
}

// ---------------- fused prep: convert x, Wqkv^T, Wout^T, cond proj ----------------
// blocks [0,4096): x->bf16 ; [4096,7168): WqkvT ; [7168,8192): WoutT ; [8192,8224): ek/ev
__global__ __launch_bounds__(256) void prep_kernel(
    const float* __restrict__ x, const float* __restrict__ Wqkv,
    const float* __restrict__ Wout, const float* __restrict__ label,
    const float* __restrict__ Wk, const float* __restrict__ Wv,
    u16* __restrict__ xb, u16* __restrict__ WqkvT, u16* __restrict__ WoutT,
    u16* __restrict__ ek, u16* __restrict__ ev, float qscale) {
  const int b = blockIdx.x;
  if (b < 4096) {
    int i = (b * 256 + threadIdx.x) * 8;
    float4 a = *(const float4*)(x + i);
    float4 c = *(const float4*)(x + i + 4);
    union { u16 u[8]; uint4 v; } r;
    r.u[0] = f2bf(a.x); r.u[1] = f2bf(a.y); r.u[2] = f2bf(a.z); r.u[3] = f2bf(a.w);
    r.u[4] = f2bf(c.x); r.u[5] = f2bf(c.y); r.u[6] = f2bf(c.z); r.u[7] = f2bf(c.w);
    *(uint4*)(xb + i) = r.v;
  } else if (b < 7168) {
    int id = (b - 4096) * 256 + threadIdx.x;
    int k = id & 511, nn = id >> 9;                 // K=512
    float v = Wqkv[(size_t)k * 1536 + nn];
    if (nn < 512) v *= qscale;
    WqkvT[id] = f2bf(v);
  } else if (b < 8192) {
    int id = (b - 7168) * 256 + threadIdx.x;
    int k = id & 511, nn = id >> 9;
    WoutT[id] = f2bf(Wout[(size_t)k * 512 + nn]);
  } else {
    int bb = b - 8192;
    int row = bb & 15;
    const float* W = (bb & 16) ? Wv : Wk;
    u16* o = (bb & 16) ? ev : ek;
    int c0 = threadIdx.x, c1 = threadIdx.x + 256;
    float a0 = 0.f, a1 = 0.f;
    for (int k = 0; k < 512; ++k) {
      float lv = label[row * 512 + k];
      const float* wr = W + (size_t)k * 512;
      a0 = fmaf(lv, wr[c0], a0);
      a1 = fmaf(lv, wr[c1], a1);
    }
    o[row * 512 + c0] = f2bf(a0);
    o[row * 512 + c1] = f2bf(a1);
  }
}

// ---------------- GEMM v2: BM=128 x BN=256, BK=64, 8 waves, dbuf + swizzled LDS ----------------
// C[M][N] = A[M][K] @ B^T[N][K].  MODE 0: qkv split-store.  MODE 1: fp32 store.
template <int MODE>
__global__ __launch_bounds__(512, 2) void gemm_bt_kernel(
    const u16* __restrict__ A, const u16* __restrict__ B,
    u16* __restrict__ OQ, u16* __restrict__ OKb, u16* __restrict__ OVT,
    float* __restrict__ OF, int K, int N) {
  __shared__ __align__(16) u16 As[2][128 * 64];
  __shared__ __align__(16) u16 Bs[2][256 * 64];
  const int tid = threadIdx.x;  // 0..511
  const int w = tid >> 6, lane = tid & 63;
  const int l15 = lane & 15, lg = lane >> 4;
  const int wr = w >> 2, wc = w & 3;  // 2M x 4N wave grid

  constexpr int NBY = (MODE == 0) ? 6 : 2;
  // XCD-chunked bijective swizzle, by fastest (A-panel L2 reuse per XCD)
  const int q8 = gridDim.x >> 3;
  const int cf = blockIdx.x;
  const int wg = (cf & 7) * q8 + (cf >> 3);
  const int bx = wg / NBY, by = wg % NBY;

  // staging: thread -> row tid>>3 (64 rows/round), 16B chunk tid&7, XOR-swizzled source
  const int srow = tid >> 3, schunk = tid & 7;
  const u16* Ag = A + (size_t)(bx * 128 + srow) * K + ((schunk ^ (srow & 7)) * 8);
  const u16* Bg = B + (size_t)(by * 256 + srow) * K + ((schunk ^ (srow & 7)) * 8);

  f32x4 acc[4][4] = {};

  const int nt = K >> 6;
#define STAGE(buf, k0)                                                     \
  {                                                                        \
    gload_lds16(Ag + (k0), &As[buf][(w * 8) * 64]);                        \
    gload_lds16(Ag + (k0) + (size_t)64 * K, &As[buf][(64 + w * 8) * 64]);  \
    _Pragma("unroll") for (int r = 0; r < 4; ++r)                          \
        gload_lds16(Bg + (k0) + (size_t)(r * 64) * K,                      \
                    &Bs[buf][(r * 64 + w * 8) * 64]);                      \
  }

  STAGE(0, 0);

  for (int t = 0; t < nt; ++t) {
    asm volatile("s_waitcnt vmcnt(0)" ::: "memory");
    __builtin_amdgcn_s_barrier();
    __builtin_amdgcn_sched_barrier(0);
    if (t + 1 < nt) STAGE((t + 1) & 1, (t + 1) * 64);

    const u16* Ab = &As[t & 1][0];
    const u16* Bb = &Bs[t & 1][0];
    bf16x8 a[4][2], b[4][2];
#pragma unroll
    for (int mi = 0; mi < 4; ++mi) {
      const int row = wr * 64 + mi * 16 + l15;
#pragma unroll
      for (int ks = 0; ks < 2; ++ks)
        a[mi][ks] = *(const bf16x8*)&Ab[row * 64 + (((ks * 4 + lg) ^ (row & 7)) * 8)];
    }
#pragma unroll
    for (int ni = 0; ni < 4; ++ni) {
      const int row = wc * 64 + ni * 16 + l15;
#pragma unroll
      for (int ks = 0; ks < 2; ++ks)
        b[ni][ks] = *(const bf16x8*)&Bb[row * 64 + (((ks * 4 + lg) ^ (row & 7)) * 8)];
    }
    __builtin_amdgcn_s_setprio(1);
#pragma unroll
    for (int ks = 0; ks < 2; ++ks)
#pragma unroll
      for (int mi = 0; mi < 4; ++mi)
#pragma unroll
        for (int ni = 0; ni < 4; ++ni)
          acc[mi][ni] = __builtin_amdgcn_mfma_f32_16x16x32_bf16(a[mi][ks], b[ni][ks], acc[mi][ni], 0, 0, 0);
    __builtin_amdgcn_s_setprio(0);
  }
#undef STAGE

  const int row0 = bx * 128 + wr * 64 + lg * 4;
  if constexpr (MODE == 1) {
#pragma unroll
    for (int mi = 0; mi < 4; ++mi)
#pragma unroll
      for (int ni = 0; ni < 4; ++ni) {
        int col = by * 256 + wc * 64 + ni * 16 + l15;
#pragma unroll
        for (int r = 0; r < 4; ++r)
          OF[(size_t)(row0 + mi * 16 + r) * N + col] = acc[mi][ni][r];
      }
  } else {
#pragma unroll
    for (int mi = 0; mi < 4; ++mi)
#pragma unroll
      for (int ni = 0; ni < 4; ++ni) {
        const int gcol = by * 256 + wc * 64 + ni * 16 + l15;
        const int sect = gcol >> 9;      // 0=q, 1=k, 2=v
        const int colL = gcol & 511;
        if (sect < 2) {
          u16* O = sect ? OKb : OQ;
#pragma unroll
          for (int r = 0; r < 4; ++r)
            O[(size_t)(row0 + mi * 16 + r) * 512 + colL] = f2bf(acc[mi][ni][r]);
        } else {
          int h = colL >> 6, dh = colL & 63;
          int rr = row0 + mi * 16;
          int bn = rr >> 10, t0 = rr & 1023;
          ushort4 pk;
          pk.x = f2bf(acc[mi][ni][0]);
          pk.y = f2bf(acc[mi][ni][1]);
          pk.z = f2bf(acc[mi][ni][2]);
          pk.w = f2bf(acc[mi][ni][3]);
          *(ushort4*)&OVT[(size_t)((bn * 8 + h) * 64 + dh) * 1024 + t0] = pk;
        }
      }
  }
}

// ---------------- fused flash attention v4: 32x32 MFMA, in-register P (T12) ----------------
// grid: 512 = 128 heads x 4 q-tiles of 256. block: 256 (4 waves x 64 q).
__global__ __launch_bounds__(256, 2) void attn_kernel(
    const u16* __restrict__ Qb, const u16* __restrict__ Kb, const u16* __restrict__ VTb,
    const u16* __restrict__ ekb, const u16* __restrict__ evb, u16* __restrict__ Ob) {
  __shared__ __align__(16) u16 Kl[64 * 64];
  __shared__ __align__(16) u16 Vl[64 * 64];

  const int tid = threadIdx.x;
  const int w = tid >> 6, lane = tid & 63;
  const int l31 = lane & 31, hi = lane >> 5;
  const int lb = (blockIdx.x & 7) * 64 + (blockIdx.x >> 3);
  const int head = lb >> 2, qt = lb & 3;
  const int bn = head >> 3, h = head & 7;
  const int q0 = qt * 256 + w * 64;

  const int sr = tid >> 3, sj = tid & 7;
  const int sdst = (sj ^ (sr & 7)) * 8;
  const u16* KgA = Kb + (size_t)(bn * 1024 + sr) * 512 + h * 64 + sj * 8;
  const u16* VgA = VTb + (size_t)(head * 64 + sr) * 1024 + sj * 8;
  u16* KlD = &Kl[sr * 64 + sdst];
  u16* VlD = &Vl[sr * 64 + sdst];

  uint4 kp0, kp1, vp0, vp1;
  {
    kp0 = *(const uint4*)(KgA);
    kp1 = *(const uint4*)(KgA + (size_t)32 * 512);
    vp0 = *(const uint4*)(VgA);
    vp1 = *(const uint4*)(VgA + (size_t)32 * 1024);
  }

  bf16x8 qf[2][4];
#pragma unroll
  for (int qs = 0; qs < 2; ++qs)
#pragma unroll
    for (int c = 0; c < 4; ++c)
      qf[qs][c] = *(const bf16x8*)(Qb + (size_t)(bn * 1024 + q0 + qs * 32 + l31) * 512 +
                                   h * 64 + c * 16 + hi * 8);

  bf16x8 bones1;
  {
    union { u16 u[8]; bf16x8 v; } ob;
#pragma unroll
    for (int j = 0; j < 8; ++j) ob.u[j] = (u16)0x3F80;
    bones1 = ob.v;
  }

  f32x16 acc[2][2];
  f32x16 acc5[2];
  {
    float dot[2] = {0.f, 0.f};
#pragma unroll
    for (int c = 0; c < 4; ++c) {
      bf16x8 ekf = *(const bf16x8*)(ekb + bn * 512 + h * 64 + c * 16 + hi * 8);
#pragma unroll
      for (int qs = 0; qs < 2; ++qs)
#pragma unroll
        for (int j = 0; j < 8; ++j)
          dot[qs] += (float)qf[qs][c][j] * (float)ekf[j];
    }
    union { u16 u[8]; bf16x8 v; } pef[2], evf[2];
#pragma unroll
    for (int qs = 0; qs < 2; ++qs) {
      uint32_t a = __builtin_bit_cast(uint32_t, dot[qs]), b = a;
      plswap(a, b);
      float part = (lane < 32) ? __builtin_bit_cast(float, b) : __builtin_bit_cast(float, a);
      float pe = exp2_fast(dot[qs] + part);
#pragma unroll
      for (int j = 0; j < 8; ++j) pef[qs].u[j] = 0;
      if (hi == 0) pef[qs].u[0] = f2bf(pe);
    }
#pragma unroll
    for (int dt = 0; dt < 2; ++dt) {
#pragma unroll
      for (int j = 0; j < 8; ++j) evf[dt].u[j] = 0;
      if (hi == 0) evf[dt].u[0] = evb[bn * 512 + h * 64 + dt * 32 + l31];
    }
    f32x16 z = {};
#pragma unroll
    for (int qs = 0; qs < 2; ++qs) {
#pragma unroll
      for (int dt = 0; dt < 2; ++dt)
        acc[qs][dt] = __builtin_amdgcn_mfma_f32_32x32x16_bf16(pef[qs].v, evf[dt].v, z, 0, 0, 0);
      acc5[qs] = __builtin_amdgcn_mfma_f32_32x32x16_bf16(pef[qs].v, bones1, z, 0, 0, 0);
    }
  }

  for (int jt = 0; jt < 16; ++jt) {
    __syncthreads();
    *(uint4*)(KlD) = kp0;
    *(uint4*)(KlD + 32 * 64) = kp1;
    *(uint4*)(VlD) = vp0;
    *(uint4*)(VlD + 32 * 64) = vp1;
    __syncthreads();

    if (jt < 15) {
      const int j0 = (jt + 1) * 64;
      kp0 = *(const uint4*)(KgA + (size_t)j0 * 512);
      kp1 = *(const uint4*)(KgA + (size_t)(j0 + 32) * 512);
      vp0 = *(const uint4*)(VgA + j0);
      vp1 = *(const uint4*)(VgA + j0 + (size_t)32 * 1024);
    }

#pragma unroll
    for (int sub = 0; sub < 2; ++sub) {
      const int rk = sub * 32 + l31;
      bf16x8 kb[4];
#pragma unroll
      for (int c = 0; c < 4; ++c)
        kb[c] = *(const bf16x8*)&Kl[rk * 64 + (((c * 2 + hi) ^ (rk & 7)) * 8)];

      f32x16 s[2] = {};
#pragma unroll
      for (int qs = 0; qs < 2; ++qs)
#pragma unroll
        for (int c = 0; c < 4; ++c)
          s[qs] = __builtin_amdgcn_mfma_f32_32x32x16_bf16(kb[c], qf[qs][c], s[qs], 0, 0, 0);

      bf16x8 pa[2][2];
#pragma unroll
      for (int qs = 0; qs < 2; ++qs) {
        uint32_t wd[8];
#pragma unroll
        for (int i = 0; i < 8; ++i)
          wd[i] = cvtpk(exp2_fast(s[qs][2 * i]), exp2_fast(s[qs][2 * i + 1]));
        plswap(wd[0], wd[2]);
        plswap(wd[1], wd[3]);
        plswap(wd[4], wd[6]);
        plswap(wd[5], wd[7]);
        union { uint32_t w[4]; bf16x8 v; } f0, f1;
        f0.w[0] = wd[0]; f0.w[1] = wd[1]; f0.w[2] = wd[2]; f0.w[3] = wd[3];
        f1.w[0] = wd[4]; f1.w[1] = wd[5]; f1.w[2] = wd[6]; f1.w[3] = wd[7];
        pa[qs][0] = f0.v;
        pa[qs][1] = f1.v;
      }

#pragma unroll
      for (int dt = 0; dt < 2; ++dt) {
        const int rv = dt * 32 + l31;
#pragma unroll
        for (int ch = 0; ch < 2; ++ch) {
          bf16x8 vb = *(const bf16x8*)&Vl[rv * 64 + (((sub * 4 + ch * 2 + hi) ^ (rv & 7)) * 8)];
#pragma unroll
          for (int qs = 0; qs < 2; ++qs)
            acc[qs][dt] = __builtin_amdgcn_mfma_f32_32x32x16_bf16(pa[qs][ch], vb, acc[qs][dt], 0, 0, 0);
        }
      }
#pragma unroll
      for (int qs = 0; qs < 2; ++qs)
#pragma unroll
        for (int ch = 0; ch < 2; ++ch)
          acc5[qs] = __builtin_amdgcn_mfma_f32_32x32x16_bf16(pa[qs][ch], bones1, acc5[qs], 0, 0, 0);
    }
  }

#pragma unroll
  for (int qs = 0; qs < 2; ++qs)
#pragma unroll
    for (int r = 0; r < 16; ++r) {
      const float inv = 1.0f / acc5[qs][r];
      const int q = q0 + qs * 32 + (r & 3) + 8 * (r >> 2) + 4 * hi;
      u16* op = Ob + (size_t)(bn * 1024 + q) * 512 + h * 64 + l31;
      op[0] = f2bf(acc[qs][0][r] * inv);
      op[32] = f2bf(acc[qs][1][r] * inv);
    }
}

// ---------------- launcher ----------------
extern "C" void kernel_launch(void* const* d_in, const int* in_sizes, int n_in,
                              void* d_out, int out_size, void* d_ws, size_t ws_size,
                              hipStream_t stream) {
  (void)in_sizes; (void)n_in; (void)out_size; (void)ws_size;
  const float* x     = (const float*)d_in[0];
  const float* label = (const float*)d_in[1];
  const float* Wqkv  = (const float*)d_in[2];
  const float* Wk    = (const float*)d_in[3];
  const float* Wv    = (const float*)d_in[4];
  const float* Wout  = (const float*)d_in[5];
  float* out = (float*)d_out;

  char* ws = (char*)d_ws;
  u16* xb    = (u16*)(ws);                 // 16 MB, reused as attention-out after GEMM1
  u16* WqkvT = (u16*)(ws + 16777216);      // 1.5 MB
  u16* WoutT = (u16*)(ws + 18350080);      // 0.5 MB
  u16* ekb   = (u16*)(ws + 18874368);      // 16 KB
  u16* evb   = (u16*)(ws + 18890752);      // 16 KB
  u16* Qbuf  = (u16*)(ws + 18907136);      // 16 MB
  u16* Kbuf  = (u16*)(ws + 35684352);      // 16 MB
  u16* VTbuf = (u16*)(ws + 52461568);      // 16 MB

  const float qscale = 0.125f * 1.4426950408889634f;

  prep_kernel<<<8224, 256, 0, stream>>>(x, Wqkv, Wout, label, Wk, Wv,
                                        xb, WqkvT, WoutT, ekb, evb, qscale);

  gemm_bt_kernel<0><<<768, 512, 0, stream>>>(xb, WqkvT, Qbuf, Kbuf, VTbuf, nullptr, 512, 1536);

  attn_kernel<<<512, 256, 0, stream>>>(Qbuf, Kbuf, VTbuf, ekb, evb, xb);

  gemm_bt_kernel<1><<<256, 512, 0, stream>>>(xb, WoutT, nullptr, nullptr, nullptr, out, 512, 512);
}

// Round 8
// 122.427 us; speedup vs baseline: 1.6224x; 1.1432x over previous
//
#include <hip/hip_runtime.h>
#include <stdint.h>

typedef unsigned short u16;
typedef __bf16 bf16x8 __attribute__((ext_vector_type(8)));
typedef float f32x4 __attribute__((ext_vector_type(4)));
typedef float f32x16 __attribute__((ext_vector_type(16)));

__device__ __forceinline__ u16 f2bf(float f) {
  uint32_t u = __builtin_bit_cast(uint32_t, f);
  u += 0x7FFFu + ((u >> 16) & 1u);
  return (u16)(u >> 16);
}
__device__ __forceinline__ float bf2f(u16 v) {
  return __builtin_bit_cast(float, ((uint32_t)v) << 16);
}

#if __has_builtin(__builtin_amdgcn_exp2f)
__device__ __forceinline__ float exp2_fast(float x) { return __builtin_amdgcn_exp2f(x); }
#else
__device__ __forceinline__ float exp2_fast(float x) { return exp2f(x); }
#endif

__device__ __forceinline__ void gload_lds16(const u16* g, u16* l) {
  __builtin_amdgcn_global_load_lds(
      (const __attribute__((address_space(1))) uint32_t*)g,
      (__attribute__((address_space(3))) uint32_t*)l, 16, 0, 0);
}

__device__ __forceinline__ uint32_t cvtpk(float lo, float hi) {
  uint32_t r;
  asm("v_cvt_pk_bf16_f32 %0, %1, %2" : "=v"(r) : "v"(lo), "v"(hi));
  return r;
}
// v_permlane32_swap_b32: a.row1 <-> b.row0  (rows = 32-lane halves)
__device__ __forceinline__ void plswap(uint32_t& a, uint32_t& b) {
  asm volatile("v_permlane32_swap_b32 %0, %1" : "+v"(a), "+v"(b));
}

// ---------------- fused prep ----------------
// [0,4096): x->bf16 ; [4096,7168): WqkvT ; [7168,8192): WoutT ; [8192,8448): cond proj
__global__ __launch_bounds__(256) void prep_kernel(
    const float* __restrict__ x, const float* __restrict__ Wqkv,
    const float* __restrict__ Wout, const float* __restrict__ label,
    const float* __restrict__ Wk, const float* __restrict__ Wv,
    u16* __restrict__ xb, u16* __restrict__ WqkvT, u16* __restrict__ WoutT,
    u16* __restrict__ ek, u16* __restrict__ ev, float qscale) {
  const int b = blockIdx.x;
  if (b < 4096) {
    int i = (b * 256 + threadIdx.x) * 8;
    float4 a = *(const float4*)(x + i);
    float4 c = *(const float4*)(x + i + 4);
    union { u16 u[8]; uint4 v; } r;
    r.u[0] = f2bf(a.x); r.u[1] = f2bf(a.y); r.u[2] = f2bf(a.z); r.u[3] = f2bf(a.w);
    r.u[4] = f2bf(c.x); r.u[5] = f2bf(c.y); r.u[6] = f2bf(c.z); r.u[7] = f2bf(c.w);
    *(uint4*)(xb + i) = r.v;
  } else if (b < 7168) {
    int id = (b - 4096) * 256 + threadIdx.x;
    int k = id & 511, nn = id >> 9;
    float v = Wqkv[(size_t)k * 1536 + nn];
    if (nn < 512) v *= qscale;
    WqkvT[id] = f2bf(v);
  } else if (b < 8192) {
    int id = (b - 7168) * 256 + threadIdx.x;
    int k = id & 511, nn = id >> 9;
    WoutT[id] = f2bf(Wout[(size_t)k * 512 + nn]);
  } else {
    // cond proj: 256 blocks = 2 (k/v) x 16 rows x 8 col-chunks; 4-way K-split + LDS reduce
    __shared__ float sdata[256];
    const int bb = b - 8192;
    const int chunk = bb & 7, row = (bb >> 3) & 15;
    const float* W = (bb & 128) ? Wv : Wk;
    u16* o = (bb & 128) ? ev : ek;
    const int tid = threadIdx.x;
    const int col = chunk * 64 + (tid & 63);
    const int ks = tid >> 6;  // 0..3, 128 k each
    const float* lr = label + row * 512 + ks * 128;
    const float* wp = W + (size_t)(ks * 128) * 512 + col;
    float acc = 0.f;
#pragma unroll 8
    for (int i = 0; i < 128; ++i)
      acc = fmaf(lr[i], wp[(size_t)i * 512], acc);
    sdata[tid] = acc;
    __syncthreads();
    if (tid < 64) {
      float t = sdata[tid] + sdata[tid + 64] + sdata[tid + 128] + sdata[tid + 192];
      o[row * 512 + chunk * 64 + tid] = f2bf(t);
    }
  }
}

// ---------------- GEMM v3: 128x256, BK=64, 8 waves, triple-buffer counted-vmcnt ----------------
// C[M][N] = A[M][K] @ B^T[N][K].  MODE 0: qkv split-store.  MODE 1: fp32 store.
template <int MODE>
__global__ __launch_bounds__(512, 2) void gemm_bt_kernel(
    const u16* __restrict__ A, const u16* __restrict__ B,
    u16* __restrict__ OQ, u16* __restrict__ OKb, u16* __restrict__ OVT,
    float* __restrict__ OF, int K, int N) {
  __shared__ __align__(16) u16 As[3][128 * 64];
  __shared__ __align__(16) u16 Bs[3][256 * 64];
  const int tid = threadIdx.x;  // 0..511
  const int w = tid >> 6, lane = tid & 63;
  const int l15 = lane & 15, lg = lane >> 4;
  const int wr = w >> 2, wc = w & 3;  // 2M x 4N wave grid

  constexpr int NBY = (MODE == 0) ? 6 : 2;
  const int q8 = gridDim.x >> 3;
  const int cf = blockIdx.x;
  const int wg = (cf & 7) * q8 + (cf >> 3);
  const int bx = wg / NBY, by = wg % NBY;

  // staging: row tid>>3 (64 rows/round), 16B chunk tid&7, XOR-swizzled source
  const int srow = tid >> 3, schunk = tid & 7;
  const u16* Ag = A + (size_t)(bx * 128 + srow) * K + ((schunk ^ (srow & 7)) * 8);
  const u16* Bg = B + (size_t)(by * 256 + srow) * K + ((schunk ^ (srow & 7)) * 8);

  f32x4 acc[4][4] = {};

  const int nt = K >> 6;  // 8
#define STAGE(buf, k0)                                                      \
  {                                                                         \
    gload_lds16(Ag + (k0), &As[buf][(w * 8) * 64]);                         \
    gload_lds16(Ag + (k0) + (size_t)64 * K, &As[buf][(64 + w * 8) * 64]);   \
    _Pragma("unroll") for (int r = 0; r < 4; ++r)                           \
        gload_lds16(Bg + (k0) + (size_t)(r * 64) * K,                       \
                    &Bs[buf][(r * 64 + w * 8) * 64]);                       \
  }
#define COMPUTE(cb)                                                               \
  {                                                                               \
    const u16* Ab = &As[cb][0];                                                   \
    const u16* Bb = &Bs[cb][0];                                                   \
    bf16x8 a[4][2], b[4][2];                                                      \
    _Pragma("unroll") for (int mi = 0; mi < 4; ++mi) {                            \
      const int row = wr * 64 + mi * 16 + l15;                                    \
      _Pragma("unroll") for (int ks = 0; ks < 2; ++ks)                            \
          a[mi][ks] = *(const bf16x8*)&Ab[row * 64 + (((ks * 4 + lg) ^ (row & 7)) * 8)]; \
    }                                                                             \
    _Pragma("unroll") for (int ni = 0; ni < 4; ++ni) {                            \
      const int row = wc * 64 + ni * 16 + l15;                                    \
      _Pragma("unroll") for (int ks = 0; ks < 2; ++ks)                            \
          b[ni][ks] = *(const bf16x8*)&Bb[row * 64 + (((ks * 4 + lg) ^ (row & 7)) * 8)]; \
    }                                                                             \
    __builtin_amdgcn_s_setprio(1);                                                \
    _Pragma("unroll") for (int ks = 0; ks < 2; ++ks)                              \
        _Pragma("unroll") for (int mi = 0; mi < 4; ++mi)                          \
            _Pragma("unroll") for (int ni = 0; ni < 4; ++ni)                      \
                acc[mi][ni] = __builtin_amdgcn_mfma_f32_16x16x32_bf16(             \
                    a[mi][ks], b[ni][ks], acc[mi][ni], 0, 0, 0);                  \
    __builtin_amdgcn_s_setprio(0);                                                \
  }

  // prologue: 2 tiles in flight (12 vm-ops/wave)
  STAGE(0, 0);
  STAGE(1, 64);

  int cr = 0, cw = 2;
  for (int t = 0; t < nt - 1; ++t) {
    // wait for STAGE(t): leave the 6 ops of STAGE(t+1) in flight
    asm volatile("s_waitcnt vmcnt(6)" ::: "memory");
    __builtin_amdgcn_s_barrier();
    __builtin_amdgcn_sched_barrier(0);
    if (t + 2 < nt) STAGE(cw, (t + 2) * 64);
    COMPUTE(cr);
    cr = (cr == 2) ? 0 : cr + 1;
    cw = (cw == 2) ? 0 : cw + 1;
  }
  asm volatile("s_waitcnt vmcnt(0)" ::: "memory");
  __builtin_amdgcn_s_barrier();
  __builtin_amdgcn_sched_barrier(0);
  COMPUTE(cr);
#undef STAGE
#undef COMPUTE

  const int row0 = bx * 128 + wr * 64 + lg * 4;
  if constexpr (MODE == 1) {
#pragma unroll
    for (int mi = 0; mi < 4; ++mi)
#pragma unroll
      for (int ni = 0; ni < 4; ++ni) {
        int col = by * 256 + wc * 64 + ni * 16 + l15;
#pragma unroll
        for (int r = 0; r < 4; ++r)
          OF[(size_t)(row0 + mi * 16 + r) * N + col] = acc[mi][ni][r];
      }
  } else {
#pragma unroll
    for (int mi = 0; mi < 4; ++mi)
#pragma unroll
      for (int ni = 0; ni < 4; ++ni) {
        const int gcol = by * 256 + wc * 64 + ni * 16 + l15;
        const int sect = gcol >> 9;      // 0=q, 1=k, 2=v
        const int colL = gcol & 511;
        if (sect < 2) {
          u16* O = sect ? OKb : OQ;
#pragma unroll
          for (int r = 0; r < 4; ++r)
            O[(size_t)(row0 + mi * 16 + r) * 512 + colL] = f2bf(acc[mi][ni][r]);
        } else {
          int h = colL >> 6, dh = colL & 63;
          int rr = row0 + mi * 16;
          int bn = rr >> 10, t0 = rr & 1023;
          ushort4 pk;
          pk.x = f2bf(acc[mi][ni][0]);
          pk.y = f2bf(acc[mi][ni][1]);
          pk.z = f2bf(acc[mi][ni][2]);
          pk.w = f2bf(acc[mi][ni][3]);
          *(ushort4*)&OVT[(size_t)((bn * 8 + h) * 64 + dh) * 1024 + t0] = pk;
        }
      }
  }
}

// ---------------- fused flash attention v4: 32x32 MFMA, in-register P (T12) ----------------
__global__ __launch_bounds__(256, 2) void attn_kernel(
    const u16* __restrict__ Qb, const u16* __restrict__ Kb, const u16* __restrict__ VTb,
    const u16* __restrict__ ekb, const u16* __restrict__ evb, u16* __restrict__ Ob) {
  __shared__ __align__(16) u16 Kl[64 * 64];
  __shared__ __align__(16) u16 Vl[64 * 64];

  const int tid = threadIdx.x;
  const int w = tid >> 6, lane = tid & 63;
  const int l31 = lane & 31, hi = lane >> 5;
  const int lb = (blockIdx.x & 7) * 64 + (blockIdx.x >> 3);
  const int head = lb >> 2, qt = lb & 3;
  const int bn = head >> 3, h = head & 7;
  const int q0 = qt * 256 + w * 64;

  const int sr = tid >> 3, sj = tid & 7;
  const int sdst = (sj ^ (sr & 7)) * 8;
  const u16* KgA = Kb + (size_t)(bn * 1024 + sr) * 512 + h * 64 + sj * 8;
  const u16* VgA = VTb + (size_t)(head * 64 + sr) * 1024 + sj * 8;
  u16* KlD = &Kl[sr * 64 + sdst];
  u16* VlD = &Vl[sr * 64 + sdst];

  uint4 kp0, kp1, vp0, vp1;
  {
    kp0 = *(const uint4*)(KgA);
    kp1 = *(const uint4*)(KgA + (size_t)32 * 512);
    vp0 = *(const uint4*)(VgA);
    vp1 = *(const uint4*)(VgA + (size_t)32 * 1024);
  }

  bf16x8 qf[2][4];
#pragma unroll
  for (int qs = 0; qs < 2; ++qs)
#pragma unroll
    for (int c = 0; c < 4; ++c)
      qf[qs][c] = *(const bf16x8*)(Qb + (size_t)(bn * 1024 + q0 + qs * 32 + l31) * 512 +
                                   h * 64 + c * 16 + hi * 8);

  bf16x8 bones1;
  {
    union { u16 u[8]; bf16x8 v; } ob;
#pragma unroll
    for (int j = 0; j < 8; ++j) ob.u[j] = (u16)0x3F80;
    bones1 = ob.v;
  }

  f32x16 acc[2][2];
  f32x16 acc5[2];
  {
    float dot[2] = {0.f, 0.f};
#pragma unroll
    for (int c = 0; c < 4; ++c) {
      bf16x8 ekf = *(const bf16x8*)(ekb + bn * 512 + h * 64 + c * 16 + hi * 8);
#pragma unroll
      for (int qs = 0; qs < 2; ++qs)
#pragma unroll
        for (int j = 0; j < 8; ++j)
          dot[qs] += (float)qf[qs][c][j] * (float)ekf[j];
    }
    union { u16 u[8]; bf16x8 v; } pef[2], evf[2];
#pragma unroll
    for (int qs = 0; qs < 2; ++qs) {
      uint32_t a = __builtin_bit_cast(uint32_t, dot[qs]), b = a;
      plswap(a, b);
      float part = (lane < 32) ? __builtin_bit_cast(float, b) : __builtin_bit_cast(float, a);
      float pe = exp2_fast(dot[qs] + part);
#pragma unroll
      for (int j = 0; j < 8; ++j) pef[qs].u[j] = 0;
      if (hi == 0) pef[qs].u[0] = f2bf(pe);
    }
#pragma unroll
    for (int dt = 0; dt < 2; ++dt) {
#pragma unroll
      for (int j = 0; j < 8; ++j) evf[dt].u[j] = 0;
      if (hi == 0) evf[dt].u[0] = evb[bn * 512 + h * 64 + dt * 32 + l31];
    }
    f32x16 z = {};
#pragma unroll
    for (int qs = 0; qs < 2; ++qs) {
#pragma unroll
      for (int dt = 0; dt < 2; ++dt)
        acc[qs][dt] = __builtin_amdgcn_mfma_f32_32x32x16_bf16(pef[qs].v, evf[dt].v, z, 0, 0, 0);
      acc5[qs] = __builtin_amdgcn_mfma_f32_32x32x16_bf16(pef[qs].v, bones1, z, 0, 0, 0);
    }
  }

  for (int jt = 0; jt < 16; ++jt) {
    __syncthreads();
    *(uint4*)(KlD) = kp0;
    *(uint4*)(KlD + 32 * 64) = kp1;
    *(uint4*)(VlD) = vp0;
    *(uint4*)(VlD + 32 * 64) = vp1;
    __syncthreads();

    if (jt < 15) {
      const int j0 = (jt + 1) * 64;
      kp0 = *(const uint4*)(KgA + (size_t)j0 * 512);
      kp1 = *(const uint4*)(KgA + (size_t)(j0 + 32) * 512);
      vp0 = *(const uint4*)(VgA + j0);
      vp1 = *(const uint4*)(VgA + j0 + (size_t)32 * 1024);
    }

#pragma unroll
    for (int sub = 0; sub < 2; ++sub) {
      const int rk = sub * 32 + l31;
      bf16x8 kb[4];
#pragma unroll
      for (int c = 0; c < 4; ++c)
        kb[c] = *(const bf16x8*)&Kl[rk * 64 + (((c * 2 + hi) ^ (rk & 7)) * 8)];

      f32x16 s[2] = {};
#pragma unroll
      for (int qs = 0; qs < 2; ++qs)
#pragma unroll
        for (int c = 0; c < 4; ++c)
          s[qs] = __builtin_amdgcn_mfma_f32_32x32x16_bf16(kb[c], qf[qs][c], s[qs], 0, 0, 0);

      bf16x8 pa[2][2];
#pragma unroll
      for (int qs = 0; qs < 2; ++qs) {
        uint32_t wd[8];
#pragma unroll
        for (int i = 0; i < 8; ++i)
          wd[i] = cvtpk(exp2_fast(s[qs][2 * i]), exp2_fast(s[qs][2 * i + 1]));
        plswap(wd[0], wd[2]);
        plswap(wd[1], wd[3]);
        plswap(wd[4], wd[6]);
        plswap(wd[5], wd[7]);
        union { uint32_t w[4]; bf16x8 v; } f0, f1;
        f0.w[0] = wd[0]; f0.w[1] = wd[1]; f0.w[2] = wd[2]; f0.w[3] = wd[3];
        f1.w[0] = wd[4]; f1.w[1] = wd[5]; f1.w[2] = wd[6]; f1.w[3] = wd[7];
        pa[qs][0] = f0.v;
        pa[qs][1] = f1.v;
      }

#pragma unroll
      for (int dt = 0; dt < 2; ++dt) {
        const int rv = dt * 32 + l31;
#pragma unroll
        for (int ch = 0; ch < 2; ++ch) {
          bf16x8 vb = *(const bf16x8*)&Vl[rv * 64 + (((sub * 4 + ch * 2 + hi) ^ (rv & 7)) * 8)];
#pragma unroll
          for (int qs = 0; qs < 2; ++qs)
            acc[qs][dt] = __builtin_amdgcn_mfma_f32_32x32x16_bf16(pa[qs][ch], vb, acc[qs][dt], 0, 0, 0);
        }
      }
#pragma unroll
      for (int qs = 0; qs < 2; ++qs)
#pragma unroll
        for (int ch = 0; ch < 2; ++ch)
          acc5[qs] = __builtin_amdgcn_mfma_f32_32x32x16_bf16(pa[qs][ch], bones1, acc5[qs], 0, 0, 0);
    }
  }

#pragma unroll
  for (int qs = 0; qs < 2; ++qs)
#pragma unroll
    for (int r = 0; r < 16; ++r) {
      const float inv = 1.0f / acc5[qs][r];
      const int q = q0 + qs * 32 + (r & 3) + 8 * (r >> 2) + 4 * hi;
      u16* op = Ob + (size_t)(bn * 1024 + q) * 512 + h * 64 + l31;
      op[0] = f2bf(acc[qs][0][r] * inv);
      op[32] = f2bf(acc[qs][1][r] * inv);
    }
}

// ---------------- launcher ----------------
extern "C" void kernel_launch(void* const* d_in, const int* in_sizes, int n_in,
                              void* d_out, int out_size, void* d_ws, size_t ws_size,
                              hipStream_t stream) {
  (void)in_sizes; (void)n_in; (void)out_size; (void)ws_size;
  const float* x     = (const float*)d_in[0];
  const float* label = (const float*)d_in[1];
  const float* Wqkv  = (const float*)d_in[2];
  const float* Wk    = (const float*)d_in[3];
  const float* Wv    = (const float*)d_in[4];
  const float* Wout  = (const float*)d_in[5];
  float* out = (float*)d_out;

  char* ws = (char*)d_ws;
  u16* xb    = (u16*)(ws);                 // 16 MB, reused as attention-out after GEMM1
  u16* WqkvT = (u16*)(ws + 16777216);      // 1.5 MB
  u16* WoutT = (u16*)(ws + 18350080);      // 0.5 MB
  u16* ekb   = (u16*)(ws + 18874368);      // 16 KB
  u16* evb   = (u16*)(ws + 18890752);      // 16 KB
  u16* Qbuf  = (u16*)(ws + 18907136);      // 16 MB
  u16* Kbuf  = (u16*)(ws + 35684352);      // 16 MB
  u16* VTbuf = (u16*)(ws + 52461568);      // 16 MB

  const float qscale = 0.125f * 1.4426950408889634f;

  prep_kernel<<<8448, 256, 0, stream>>>(x, Wqkv, Wout, label, Wk, Wv,
                                        xb, WqkvT, WoutT, ekb, evb, qscale);

  gemm_bt_kernel<0><<<768, 512, 0, stream>>>(xb, WqkvT, Qbuf, Kbuf, VTbuf, nullptr, 512, 1536);

  attn_kernel<<<512, 256, 0, stream>>>(Qbuf, Kbuf, VTbuf, ekb, evb, xb);

  gemm_bt_kernel<1><<<256, 512, 0, stream>>>(xb, WoutT, nullptr, nullptr, nullptr, out, 512, 512);
}

// Round 9
// 120.172 us; speedup vs baseline: 1.6529x; 1.0188x over previous
//
#include <hip/hip_runtime.h>
#include <stdint.h>

typedef unsigned short u16;
typedef __bf16 bf16x8 __attribute__((ext_vector_type(8)));
typedef float f32x4 __attribute__((ext_vector_type(4)));
typedef float f32x16 __attribute__((ext_vector_type(16)));

__device__ __forceinline__ u16 f2bf(float f) {
  uint32_t u = __builtin_bit_cast(uint32_t, f);
  u += 0x7FFFu + ((u >> 16) & 1u);
  return (u16)(u >> 16);
}
__device__ __forceinline__ float bf2f(u16 v) {
  return __builtin_bit_cast(float, ((uint32_t)v) << 16);
}

#if __has_builtin(__builtin_amdgcn_exp2f)
__device__ __forceinline__ float exp2_fast(float x) { return __builtin_amdgcn_exp2f(x); }
#else
__device__ __forceinline__ float exp2_fast(float x) { return exp2f(x); }
#endif

__device__ __forceinline__ void gload_lds16(const u16* g, u16* l) {
  __builtin_amdgcn_global_load_lds(
      (const __attribute__((address_space(1))) uint32_t*)g,
      (__attribute__((address_space(3))) uint32_t*)l, 16, 0, 0);
}

__device__ __forceinline__ uint32_t cvtpk(float lo, float hi) {
  uint32_t r;
  asm("v_cvt_pk_bf16_f32 %0, %1, %2" : "=v"(r) : "v"(lo), "v"(hi));
  return r;
}
// v_permlane32_swap_b32: a.row1 <-> b.row0  (rows = 32-lane halves)
__device__ __forceinline__ void plswap(uint32_t& a, uint32_t& b) {
  asm volatile("v_permlane32_swap_b32 %0, %1" : "+v"(a), "+v"(b));
}

// ---------------- fused prep ----------------
// [0,4096): x->bf16 ; [4096,7168): WqkvT ; [7168,8192): WoutT ; [8192,8448): cond proj
__global__ __launch_bounds__(256) void prep_kernel(
    const float* __restrict__ x, const float* __restrict__ Wqkv,
    const float* __restrict__ Wout, const float* __restrict__ label,
    const float* __restrict__ Wk, const float* __restrict__ Wv,
    u16* __restrict__ xb, u16* __restrict__ WqkvT, u16* __restrict__ WoutT,
    u16* __restrict__ ek, u16* __restrict__ ev, float qscale) {
  const int b = blockIdx.x;
  if (b < 4096) {
    int i = (b * 256 + threadIdx.x) * 8;
    float4 a = *(const float4*)(x + i);
    float4 c = *(const float4*)(x + i + 4);
    union { u16 u[8]; uint4 v; } r;
    r.u[0] = f2bf(a.x); r.u[1] = f2bf(a.y); r.u[2] = f2bf(a.z); r.u[3] = f2bf(a.w);
    r.u[4] = f2bf(c.x); r.u[5] = f2bf(c.y); r.u[6] = f2bf(c.z); r.u[7] = f2bf(c.w);
    *(uint4*)(xb + i) = r.v;
  } else if (b < 7168) {
    int id = (b - 4096) * 256 + threadIdx.x;
    int k = id & 511, nn = id >> 9;
    float v = Wqkv[(size_t)k * 1536 + nn];
    if (nn < 512) v *= qscale;
    WqkvT[id] = f2bf(v);
  } else if (b < 8192) {
    int id = (b - 7168) * 256 + threadIdx.x;
    int k = id & 511, nn = id >> 9;
    WoutT[id] = f2bf(Wout[(size_t)k * 512 + nn]);
  } else {
    // cond proj: 256 blocks = 2 (k/v) x 16 rows x 8 col-chunks; 4-way K-split + LDS reduce
    __shared__ float sdata[256];
    const int bb = b - 8192;
    const int chunk = bb & 7, row = (bb >> 3) & 15;
    const float* W = (bb & 128) ? Wv : Wk;
    u16* o = (bb & 128) ? ev : ek;
    const int tid = threadIdx.x;
    const int col = chunk * 64 + (tid & 63);
    const int ks = tid >> 6;  // 0..3, 128 k each
    const float* lr = label + row * 512 + ks * 128;
    const float* wp = W + (size_t)(ks * 128) * 512 + col;
    float acc = 0.f;
#pragma unroll 8
    for (int i = 0; i < 128; ++i)
      acc = fmaf(lr[i], wp[(size_t)i * 512], acc);
    sdata[tid] = acc;
    __syncthreads();
    if (tid < 64) {
      float t = sdata[tid] + sdata[tid + 64] + sdata[tid + 128] + sdata[tid + 192];
      o[row * 512 + chunk * 64 + tid] = f2bf(t);
    }
  }
}

// ---------------- GEMM v4: BM=256 x BN(192|128), BK=64, 8 waves (2Mx4N), ----------------
// per-wave 128x(48|32); 2-buffer LDS, counted vmcnt, hoisted swizzle offsets.
// C[M][N] = A[M][K] @ B^T[N][K].  MODE 0: qkv split-store.  MODE 1: fp32 store.
template <int MODE>
__global__ __launch_bounds__(512, 2) void gemm_bt_kernel(
    const u16* __restrict__ A, const u16* __restrict__ B,
    u16* __restrict__ OQ, u16* __restrict__ OKb, u16* __restrict__ OVT,
    float* __restrict__ OF, int K, int N) {
  constexpr int BN = (MODE == 0) ? 192 : 128;
  constexpr int NI = BN / 64;      // B fragments per wave (3 | 2)
  constexpr int NRB = BN / 64;     // B staging rounds of 64 rows
  constexpr int NBY = (MODE == 0) ? 8 : 4;
  constexpr int VM = 4 + NRB;      // gload_lds per wave per STAGE

  __shared__ __align__(16) u16 As[2][256 * 64];
  __shared__ __align__(16) u16 Bs[2][BN * 64];

  const int tid = threadIdx.x;  // 0..511
  const int w = tid >> 6, lane = tid & 63;
  const int l15 = lane & 15, lg = lane >> 4;
  const int wr = w >> 2, wc = w & 3;  // 2M x 4N wave grid

  // XCD-chunked bijective swizzle, by fastest (A-panel L2 reuse per XCD)
  const int q8 = gridDim.x >> 3;
  const int wg = (blockIdx.x & 7) * q8 + (blockIdx.x >> 3);
  const int bx = wg / NBY, by = wg % NBY;

  // staging: row tid>>3 (64 rows/round), 16B chunk tid&7, XOR-swizzled source
  const int srow = tid >> 3, schunk = tid & 7;
  const u16* Ag = A + (size_t)(bx * 256 + srow) * K + ((schunk ^ (srow & 7)) * 8);
  const u16* Bg = B + (size_t)(by * BN + srow) * K + ((schunk ^ (srow & 7)) * 8);

  // hoisted swizzled LDS read offsets (loop-invariant)
  int aoff[8][2], boff[NI][2];
#pragma unroll
  for (int mi = 0; mi < 8; ++mi)
#pragma unroll
    for (int ks = 0; ks < 2; ++ks) {
      const int row = wr * 128 + mi * 16 + l15;
      aoff[mi][ks] = row * 64 + (((ks * 4 + lg) ^ (row & 7)) * 8);
    }
#pragma unroll
  for (int ni = 0; ni < NI; ++ni)
#pragma unroll
    for (int ks = 0; ks < 2; ++ks) {
      const int row = wc * (BN / 4) + ni * 16 + l15;
      boff[ni][ks] = row * 64 + (((ks * 4 + lg) ^ (row & 7)) * 8);
    }

  f32x4 acc[8][NI] = {};

  const int nt = K >> 6;
#define STAGE(buf, k0)                                                       \
  {                                                                          \
    _Pragma("unroll") for (int ra = 0; ra < 4; ++ra)                         \
        gload_lds16(Ag + (k0) + (size_t)(ra * 64) * K,                       \
                    &As[buf][(ra * 64 + w * 8) * 64]);                       \
    _Pragma("unroll") for (int rb = 0; rb < NRB; ++rb)                       \
        gload_lds16(Bg + (k0) + (size_t)(rb * 64) * K,                       \
                    &Bs[buf][(rb * 64 + w * 8) * 64]);                       \
  }
#define COMPUTE(cb)                                                          \
  {                                                                          \
    const u16* Ab = &As[cb][0];                                              \
    const u16* Bb = &Bs[cb][0];                                              \
    _Pragma("unroll") for (int ks = 0; ks < 2; ++ks) {                       \
      bf16x8 a[8], b[NI];                                                    \
      _Pragma("unroll") for (int mi = 0; mi < 8; ++mi)                       \
          a[mi] = *(const bf16x8*)&Ab[aoff[mi][ks]];                         \
      _Pragma("unroll") for (int ni = 0; ni < NI; ++ni)                      \
          b[ni] = *(const bf16x8*)&Bb[boff[ni][ks]];                         \
      __builtin_amdgcn_s_setprio(1);                                         \
      _Pragma("unroll") for (int mi = 0; mi < 8; ++mi)                       \
          _Pragma("unroll") for (int ni = 0; ni < NI; ++ni)                  \
              acc[mi][ni] = __builtin_amdgcn_mfma_f32_16x16x32_bf16(          \
                  a[mi], b[ni], acc[mi][ni], 0, 0, 0);                       \
      __builtin_amdgcn_s_setprio(0);                                         \
    }                                                                        \
  }

  STAGE(0, 0);
  STAGE(1, 64);

  for (int t = 0; t < nt - 1; ++t) {
    // wait for STAGE(t); leave STAGE(t+1)'s VM ops in flight
    if constexpr (VM == 7)
      asm volatile("s_waitcnt vmcnt(7)" ::: "memory");
    else
      asm volatile("s_waitcnt vmcnt(6)" ::: "memory");
    __builtin_amdgcn_s_barrier();
    __builtin_amdgcn_sched_barrier(0);
    COMPUTE(t & 1);
    if (t + 2 < nt) {
      __builtin_amdgcn_s_barrier();  // all waves done reading buf t&1
      __builtin_amdgcn_sched_barrier(0);
      STAGE(t & 1, (t + 2) * 64);    // latency hides under COMPUTE(t+1)
    }
  }
  asm volatile("s_waitcnt vmcnt(0)" ::: "memory");
  __builtin_amdgcn_s_barrier();
  __builtin_amdgcn_sched_barrier(0);
  COMPUTE((nt - 1) & 1);
#undef STAGE
#undef COMPUTE

  const int row0 = bx * 256 + wr * 128 + lg * 4;
  if constexpr (MODE == 1) {
#pragma unroll
    for (int mi = 0; mi < 8; ++mi)
#pragma unroll
      for (int ni = 0; ni < NI; ++ni) {
        int col = by * BN + wc * (BN / 4) + ni * 16 + l15;
#pragma unroll
        for (int r = 0; r < 4; ++r)
          OF[(size_t)(row0 + mi * 16 + r) * N + col] = acc[mi][ni][r];
      }
  } else {
#pragma unroll
    for (int mi = 0; mi < 8; ++mi)
#pragma unroll
      for (int ni = 0; ni < NI; ++ni) {
        const int gcol = by * BN + wc * (BN / 4) + ni * 16 + l15;
        const int sect = gcol >> 9;      // 0=q, 1=k, 2=v
        const int colL = gcol & 511;
        if (sect < 2) {
          u16* O = sect ? OKb : OQ;
#pragma unroll
          for (int r = 0; r < 4; ++r)
            O[(size_t)(row0 + mi * 16 + r) * 512 + colL] = f2bf(acc[mi][ni][r]);
        } else {
          int h = colL >> 6, dh = colL & 63;
          int rr = row0 + mi * 16;
          int bn = rr >> 10, t0 = rr & 1023;
          ushort4 pk;
          pk.x = f2bf(acc[mi][ni][0]);
          pk.y = f2bf(acc[mi][ni][1]);
          pk.z = f2bf(acc[mi][ni][2]);
          pk.w = f2bf(acc[mi][ni][3]);
          *(ushort4*)&OVT[(size_t)((bn * 8 + h) * 64 + dh) * 1024 + t0] = pk;
        }
      }
  }
}

// ---------------- fused flash attention v4: 32x32 MFMA, in-register P (T12) ----------------
__global__ __launch_bounds__(256, 2) void attn_kernel(
    const u16* __restrict__ Qb, const u16* __restrict__ Kb, const u16* __restrict__ VTb,
    const u16* __restrict__ ekb, const u16* __restrict__ evb, u16* __restrict__ Ob) {
  __shared__ __align__(16) u16 Kl[64 * 64];
  __shared__ __align__(16) u16 Vl[64 * 64];

  const int tid = threadIdx.x;
  const int w = tid >> 6, lane = tid & 63;
  const int l31 = lane & 31, hi = lane >> 5;
  const int lb = (blockIdx.x & 7) * 64 + (blockIdx.x >> 3);
  const int head = lb >> 2, qt = lb & 3;
  const int bn = head >> 3, h = head & 7;
  const int q0 = qt * 256 + w * 64;

  const int sr = tid >> 3, sj = tid & 7;
  const int sdst = (sj ^ (sr & 7)) * 8;
  const u16* KgA = Kb + (size_t)(bn * 1024 + sr) * 512 + h * 64 + sj * 8;
  const u16* VgA = VTb + (size_t)(head * 64 + sr) * 1024 + sj * 8;
  u16* KlD = &Kl[sr * 64 + sdst];
  u16* VlD = &Vl[sr * 64 + sdst];

  uint4 kp0, kp1, vp0, vp1;
  {
    kp0 = *(const uint4*)(KgA);
    kp1 = *(const uint4*)(KgA + (size_t)32 * 512);
    vp0 = *(const uint4*)(VgA);
    vp1 = *(const uint4*)(VgA + (size_t)32 * 1024);
  }

  bf16x8 qf[2][4];
#pragma unroll
  for (int qs = 0; qs < 2; ++qs)
#pragma unroll
    for (int c = 0; c < 4; ++c)
      qf[qs][c] = *(const bf16x8*)(Qb + (size_t)(bn * 1024 + q0 + qs * 32 + l31) * 512 +
                                   h * 64 + c * 16 + hi * 8);

  bf16x8 bones1;
  {
    union { u16 u[8]; bf16x8 v; } ob;
#pragma unroll
    for (int j = 0; j < 8; ++j) ob.u[j] = (u16)0x3F80;
    bones1 = ob.v;
  }

  f32x16 acc[2][2];
  f32x16 acc5[2];
  {
    float dot[2] = {0.f, 0.f};
#pragma unroll
    for (int c = 0; c < 4; ++c) {
      bf16x8 ekf = *(const bf16x8*)(ekb + bn * 512 + h * 64 + c * 16 + hi * 8);
#pragma unroll
      for (int qs = 0; qs < 2; ++qs)
#pragma unroll
        for (int j = 0; j < 8; ++j)
          dot[qs] += (float)qf[qs][c][j] * (float)ekf[j];
    }
    union { u16 u[8]; bf16x8 v; } pef[2], evf[2];
#pragma unroll
    for (int qs = 0; qs < 2; ++qs) {
      uint32_t a = __builtin_bit_cast(uint32_t, dot[qs]), b = a;
      plswap(a, b);
      float part = (lane < 32) ? __builtin_bit_cast(float, b) : __builtin_bit_cast(float, a);
      float pe = exp2_fast(dot[qs] + part);
#pragma unroll
      for (int j = 0; j < 8; ++j) pef[qs].u[j] = 0;
      if (hi == 0) pef[qs].u[0] = f2bf(pe);
    }
#pragma unroll
    for (int dt = 0; dt < 2; ++dt) {
#pragma unroll
      for (int j = 0; j < 8; ++j) evf[dt].u[j] = 0;
      if (hi == 0) evf[dt].u[0] = evb[bn * 512 + h * 64 + dt * 32 + l31];
    }
    f32x16 z = {};
#pragma unroll
    for (int qs = 0; qs < 2; ++qs) {
#pragma unroll
      for (int dt = 0; dt < 2; ++dt)
        acc[qs][dt] = __builtin_amdgcn_mfma_f32_32x32x16_bf16(pef[qs].v, evf[dt].v, z, 0, 0, 0);
      acc5[qs] = __builtin_amdgcn_mfma_f32_32x32x16_bf16(pef[qs].v, bones1, z, 0, 0, 0);
    }
  }

  for (int jt = 0; jt < 16; ++jt) {
    __syncthreads();
    *(uint4*)(KlD) = kp0;
    *(uint4*)(KlD + 32 * 64) = kp1;
    *(uint4*)(VlD) = vp0;
    *(uint4*)(VlD + 32 * 64) = vp1;
    __syncthreads();

    if (jt < 15) {
      const int j0 = (jt + 1) * 64;
      kp0 = *(const uint4*)(KgA + (size_t)j0 * 512);
      kp1 = *(const uint4*)(KgA + (size_t)(j0 + 32) * 512);
      vp0 = *(const uint4*)(VgA + j0);
      vp1 = *(const uint4*)(VgA + j0 + (size_t)32 * 1024);
    }

#pragma unroll
    for (int sub = 0; sub < 2; ++sub) {
      const int rk = sub * 32 + l31;
      bf16x8 kb[4];
#pragma unroll
      for (int c = 0; c < 4; ++c)
        kb[c] = *(const bf16x8*)&Kl[rk * 64 + (((c * 2 + hi) ^ (rk & 7)) * 8)];

      f32x16 s[2] = {};
#pragma unroll
      for (int qs = 0; qs < 2; ++qs)
#pragma unroll
        for (int c = 0; c < 4; ++c)
          s[qs] = __builtin_amdgcn_mfma_f32_32x32x16_bf16(kb[c], qf[qs][c], s[qs], 0, 0, 0);

      bf16x8 pa[2][2];
#pragma unroll
      for (int qs = 0; qs < 2; ++qs) {
        uint32_t wd[8];
#pragma unroll
        for (int i = 0; i < 8; ++i)
          wd[i] = cvtpk(exp2_fast(s[qs][2 * i]), exp2_fast(s[qs][2 * i + 1]));
        plswap(wd[0], wd[2]);
        plswap(wd[1], wd[3]);
        plswap(wd[4], wd[6]);
        plswap(wd[5], wd[7]);
        union { uint32_t w[4]; bf16x8 v; } f0, f1;
        f0.w[0] = wd[0]; f0.w[1] = wd[1]; f0.w[2] = wd[2]; f0.w[3] = wd[3];
        f1.w[0] = wd[4]; f1.w[1] = wd[5]; f1.w[2] = wd[6]; f1.w[3] = wd[7];
        pa[qs][0] = f0.v;
        pa[qs][1] = f1.v;
      }

#pragma unroll
      for (int dt = 0; dt < 2; ++dt) {
        const int rv = dt * 32 + l31;
#pragma unroll
        for (int ch = 0; ch < 2; ++ch) {
          bf16x8 vb = *(const bf16x8*)&Vl[rv * 64 + (((sub * 4 + ch * 2 + hi) ^ (rv & 7)) * 8)];
#pragma unroll
          for (int qs = 0; qs < 2; ++qs)
            acc[qs][dt] = __builtin_amdgcn_mfma_f32_32x32x16_bf16(pa[qs][ch], vb, acc[qs][dt], 0, 0, 0);
        }
      }
#pragma unroll
      for (int qs = 0; qs < 2; ++qs)
#pragma unroll
        for (int ch = 0; ch < 2; ++ch)
          acc5[qs] = __builtin_amdgcn_mfma_f32_32x32x16_bf16(pa[qs][ch], bones1, acc5[qs], 0, 0, 0);
    }
  }

#pragma unroll
  for (int qs = 0; qs < 2; ++qs)
#pragma unroll
    for (int r = 0; r < 16; ++r) {
      const float inv = 1.0f / acc5[qs][r];
      const int q = q0 + qs * 32 + (r & 3) + 8 * (r >> 2) + 4 * hi;
      u16* op = Ob + (size_t)(bn * 1024 + q) * 512 + h * 64 + l31;
      op[0] = f2bf(acc[qs][0][r] * inv);
      op[32] = f2bf(acc[qs][1][r] * inv);
    }
}

// ---------------- launcher ----------------
extern "C" void kernel_launch(void* const* d_in, const int* in_sizes, int n_in,
                              void* d_out, int out_size, void* d_ws, size_t ws_size,
                              hipStream_t stream) {
  (void)in_sizes; (void)n_in; (void)out_size; (void)ws_size;
  const float* x     = (const float*)d_in[0];
  const float* label = (const float*)d_in[1];
  const float* Wqkv  = (const float*)d_in[2];
  const float* Wk    = (const float*)d_in[3];
  const float* Wv    = (const float*)d_in[4];
  const float* Wout  = (const float*)d_in[5];
  float* out = (float*)d_out;

  char* ws = (char*)d_ws;
  u16* xb    = (u16*)(ws);                 // 16 MB, reused as attention-out after GEMM1
  u16* WqkvT = (u16*)(ws + 16777216);      // 1.5 MB
  u16* WoutT = (u16*)(ws + 18350080);      // 0.5 MB
  u16* ekb   = (u16*)(ws + 18874368);      // 16 KB
  u16* evb   = (u16*)(ws + 18890752);      // 16 KB
  u16* Qbuf  = (u16*)(ws + 18907136);      // 16 MB
  u16* Kbuf  = (u16*)(ws + 35684352);      // 16 MB
  u16* VTbuf = (u16*)(ws + 52461568);      // 16 MB

  const float qscale = 0.125f * 1.4426950408889634f;

  prep_kernel<<<8448, 256, 0, stream>>>(x, Wqkv, Wout, label, Wk, Wv,
                                        xb, WqkvT, WoutT, ekb, evb, qscale);

  gemm_bt_kernel<0><<<512, 512, 0, stream>>>(xb, WqkvT, Qbuf, Kbuf, VTbuf, nullptr, 512, 1536);

  attn_kernel<<<512, 256, 0, stream>>>(Qbuf, Kbuf, VTbuf, ekb, evb, xb);

  gemm_bt_kernel<1><<<256, 512, 0, stream>>>(xb, WoutT, nullptr, nullptr, nullptr, out, 512, 512);
}